// Round 13
// baseline (1751.107 us; speedup 1.0000x reference)
//
#include <hip/hip_runtime.h>

#define NTOK 65536
#define DDIM 512
#define HDIM 1024
#define NEXP 8
#define PROJ 256
#define CAP  16384
#define NSLOT (2*NTOK)
#define LOG100 4.605170185988091f

typedef __attribute__((ext_vector_type(8))) short bf16x8;
typedef __attribute__((ext_vector_type(4))) short short4v;
typedef __attribute__((ext_vector_type(4))) float f32x4;

// ---------- helpers ----------
__device__ inline float bf2f(unsigned short u){
    union { float f; unsigned int i; } c; c.i = ((unsigned int)u) << 16; return c.f;
}
__device__ inline unsigned short f2bf(float f){
    union { float f; unsigned int i; } c; c.f = f;
    unsigned int x = c.i;
    return (unsigned short)((x + 0x7fffu + ((x >> 16) & 1u)) >> 16); // RTNE
}
__device__ inline void gload16(const void* g, void* lds){
    __builtin_amdgcn_global_load_lds(
        (const __attribute__((address_space(1))) unsigned int*)g,
        (__attribute__((address_space(3))) unsigned int*)lds, 16, 0, 0);
}

// ---------- fused init: xb = bf16(x), out = 0 ----------
__global__ void init_k(const float4* __restrict__ x, ushort4* __restrict__ xb,
                       float4* __restrict__ out){
    long i = (long)blockIdx.x * 256 + threadIdx.x;
    float4 f = x[i];
    ushort4 u; u.x = f2bf(f.x); u.y = f2bf(f.y); u.z = f2bf(f.z); u.w = f2bf(f.w);
    xb[i] = u;
    out[i] = float4{0.f, 0.f, 0.f, 0.f};
}

// ---------- generic 32x32-tiled transpose+convert body ----------
__device__ inline void trans_body(const float* in, unsigned short* out, int R, int C){
    int rbase = blockIdx.y * 32, cbase = blockIdx.x * 32;
    if (rbase >= R || cbase >= C) return;
    __shared__ float tile[32][33];
    int tx = threadIdx.x, ty = threadIdx.y;   // (32,8)
    #pragma unroll
    for (int i = 0; i < 4; i++)
        tile[ty + i*8][tx] = in[(long)(rbase + ty + i*8) * C + cbase + tx];
    __syncthreads();
    #pragma unroll
    for (int i = 0; i < 4; i++)
        out[(long)(cbase + ty + i*8) * R + rbase + tx] = f2bf(tile[tx][ty + i*8]);
}

// per-model W1/W2 transpose (lower tiers)
__global__ __launch_bounds__(256)
void trans2_k(const float* __restrict__ W1, const float* __restrict__ W2,
              unsigned short* __restrict__ W1T, unsigned short* __restrict__ W2T)
{
    int z = blockIdx.z;
    if (z < 8) trans_body(W1 + (size_t)z*DDIM*HDIM, W1T + (size_t)z*DDIM*HDIM, DDIM, HDIM);
    else       trans_body(W2 + (size_t)(z-8)*DDIM*HDIM, W2T + (size_t)(z-8)*DDIM*HDIM, HDIM, DDIM);
}

// all-model W1/W2 transpose
struct W12P { const float* W1[3]; const float* W2[3]; };
__global__ __launch_bounds__(256)
void transW12all_k(W12P wp, unsigned short* __restrict__ W1T3, unsigned short* __restrict__ W2T3)
{
    int z = blockIdx.z, m = z >> 4, piece = z & 15;
    if (piece < 8)
        trans_body(wp.W1[m] + (size_t)piece*DDIM*HDIM,
                   W1T3 + ((size_t)m*8 + piece)*DDIM*HDIM, DDIM, HDIM);
    else
        trans_body(wp.W2[m] + (size_t)(piece-8)*DDIM*HDIM,
                   W2T3 + ((size_t)m*8 + piece-8)*DDIM*HDIM, HDIM, DDIM);
}

// Wp transpose: [512][256] f32 -> [256][512] bf16, per model
struct TpArgs { const float* Wp[3]; };
__global__ __launch_bounds__(256)
void transWp_k(TpArgs ta, unsigned short* __restrict__ WpT3)
{
    int m = blockIdx.z;
    trans_body(ta.Wp[m], WpT3 + (size_t)m*PROJ*DDIM, DDIM, PROJ);
}

// ---------- normalize sim columns ----------
struct SimArgs { const float* sim[3]; };
__global__ void simn3_k(SimArgs sa, float* __restrict__ simn3){
    __shared__ float red[256];
    const float* sim = sa.sim[blockIdx.x];
    float* simn = simn3 + (size_t)blockIdx.x * PROJ * NEXP;
    int j = threadIdx.x;
    for (int e = 0; e < NEXP; e++){
        float v = sim[j*NEXP + e];
        red[j] = v*v;
        __syncthreads();
        for (int s = 128; s > 0; s >>= 1){
            if (j < s) red[j] += red[j + s];
            __syncthreads();
        }
        float nrm = sqrtf(red[0]) + 1e-12f;
        __syncthreads();
        simn[j*NEXP + e] = v / nrm;
    }
}

// ---------- W' = Wp @ simn (fp32), bd = bp @ simn ----------
struct WprodArgs { const float* Wp[3]; const float* bp[3]; };
__global__ __launch_bounds__(256)
void wprod_k(WprodArgs wa, const float* __restrict__ simn3,
             float* __restrict__ Wn3, float* __restrict__ bd3)
{
    int m = blockIdx.x;
    __shared__ float Sn[PROJ*NEXP];
    const float* Wp = wa.Wp[m];
    int t = threadIdx.x;
    for (int i = t; i < PROJ*NEXP; i += 256) Sn[i] = simn3[(size_t)m*PROJ*NEXP + i];
    __syncthreads();
    for (int r = t; r < DDIM; r += 256){
        float d[8];
        #pragma unroll
        for (int e = 0; e < 8; e++) d[e] = 0.f;
        for (int p = 0; p < PROJ; p++){
            float w = Wp[(size_t)r*PROJ + p];
            #pragma unroll
            for (int e = 0; e < 8; e++) d[e] = fmaf(w, Sn[p*8+e], d[e]);
        }
        #pragma unroll
        for (int e = 0; e < 8; e++) Wn3[((size_t)m*DDIM + r)*8 + e] = d[e];
    }
    if (t < 8){
        float s = 0.f;
        for (int p = 0; p < PROJ; p++) s = fmaf(wa.bp[m][p], Sn[p*8+t], s);
        bd3[m*8 + t] = s;
    }
}

// ---------- pss: MFMA P-GEMM, epilogue = row-norm^2 only ----------
struct PssArgs { const float* bp[3]; };
__global__ __launch_bounds__(256)
void pss_k(const unsigned short* __restrict__ WpT3, const unsigned short* __restrict__ xb,
           PssArgs pa, float* __restrict__ ssbuf)
{
    __shared__ __align__(16) short As[128*32];
    __shared__ __align__(16) short Bs[128*32];
    __shared__ float ssl[2][128];
    const int m = blockIdx.z;
    const int row0 = blockIdx.x * 128;
    const int n0 = blockIdx.y * 128;
    const unsigned short* AT = WpT3 + (size_t)m * PROJ * DDIM;
    const float* bp = pa.bp[m];

    const int t = threadIdx.x, w = t >> 6, l = t & 63;
    const int qrow = l >> 2, kc = (l & 3) * 8;
    long arowg[2], browg[2];
    #pragma unroll
    for (int q = 0; q < 2; q++){
        arowg[q] = (long)(row0 + w*32 + q*16 + qrow) * DDIM;
        browg[q] = (long)(n0   + w*32 + q*16 + qrow) * DDIM;
    }
    const int wm = (w >> 1) * 64, wn = (w & 1) * 64;
    const int fr = l & 15, fk = l >> 4;
    const int koff = fk * 8, fk4 = fk * 4;

    f32x4 acc[4][4];
    #pragma unroll
    for (int i = 0; i < 4; i++)
        #pragma unroll
        for (int j = 0; j < 4; j++) acc[i][j] = (f32x4){0.f, 0.f, 0.f, 0.f};

    for (int k0 = 0; k0 < DDIM; k0 += 32){
        __syncthreads();
        #pragma unroll
        for (int q = 0; q < 2; q++) gload16(AT + arowg[q] + k0 + kc, As + w*1024 + q*512);
        #pragma unroll
        for (int q = 0; q < 2; q++) gload16(xb + browg[q] + k0 + kc, Bs + w*1024 + q*512);
        __syncthreads();
        bf16x8 af[4], bfv[4];
        #pragma unroll
        for (int i = 0; i < 4; i++) af[i]  = *(const bf16x8*)&As[(wm + i*16 + fr)*32 + koff];
        #pragma unroll
        for (int j = 0; j < 4; j++) bfv[j] = *(const bf16x8*)&Bs[(wn + j*16 + fr)*32 + koff];
        #pragma unroll
        for (int i = 0; i < 4; i++)
            #pragma unroll
            for (int j = 0; j < 4; j++)
                acc[i][j] = __builtin_amdgcn_mfma_f32_16x16x32_bf16(af[i], bfv[j], acc[i][j], 0, 0, 0);
    }

    float part[4];
    #pragma unroll
    for (int j = 0; j < 4; j++){
        float s = 0.f;
        #pragma unroll
        for (int i = 0; i < 4; i++){
            int mc = row0 + wm + i*16 + fk4;
            float4 bb = *(const float4*)(bp + mc);
            float v0 = acc[i][j][0] + bb.x;
            float v1 = acc[i][j][1] + bb.y;
            float v2 = acc[i][j][2] + bb.z;
            float v3 = acc[i][j][3] + bb.w;
            s += v0*v0 + v1*v1 + v2*v2 + v3*v3;
        }
        s += __shfl_xor(s, 16, 64);
        s += __shfl_xor(s, 32, 64);
        part[j] = s;
    }
    if (fk == 0){
        #pragma unroll
        for (int j = 0; j < 4; j++) ssl[w >> 1][wn + j*16 + fr] = part[j];
    }
    __syncthreads();
    if (t < 128)
        ssbuf[((size_t)blockIdx.x*3 + m)*NTOK + n0 + t] = ssl[0][t] + ssl[1][t];
}

// ---------- gatefin3: k-split GEMV, wave-uniform W s_loads ----------
struct GfArgs { const float* tp[3]; };
__global__ __launch_bounds__(256)
void gatefin3_k(const float* __restrict__ x, const int* __restrict__ label,
                const float* __restrict__ Wn3, const float* __restrict__ bd3,
                const float* __restrict__ ssbuf, GfArgs gf,
                int* __restrict__ idx3, float* __restrict__ gw3)
{
    __shared__ float pd[3][64][26];
    const int t = threadIdx.x;
    const int tok = t & 63;
    const int qu = __builtin_amdgcn_readfirstlane(t >> 6);
    const int n = blockIdx.x * 64 + tok;

    float dots[3][8];
    #pragma unroll
    for (int m = 0; m < 3; m++)
        #pragma unroll
        for (int e = 0; e < 8; e++) dots[m][e] = 0.f;

    const float4* xp = (const float4*)(x + (size_t)n * DDIM + qu * 128);
    for (int c = 0; c < 8; c++){
        float4 xv[4];
        #pragma unroll
        for (int u = 0; u < 4; u++) xv[u] = xp[c*4 + u];
        #pragma unroll
        for (int kk = 0; kk < 16; kk++){
            float a = (kk & 2) ? ((kk & 1) ? xv[kk>>2].w : xv[kk>>2].z)
                               : ((kk & 1) ? xv[kk>>2].y : xv[kk>>2].x);
            int k = qu*128 + c*16 + kk;
            #pragma unroll
            for (int m = 0; m < 3; m++){
                const float* wr = Wn3 + ((size_t)m*DDIM + k)*8;
                float4 w0 = *(const float4*)wr;
                float4 w1 = *(const float4*)(wr + 4);
                dots[m][0] = fmaf(a, w0.x, dots[m][0]);
                dots[m][1] = fmaf(a, w0.y, dots[m][1]);
                dots[m][2] = fmaf(a, w0.z, dots[m][2]);
                dots[m][3] = fmaf(a, w0.w, dots[m][3]);
                dots[m][4] = fmaf(a, w1.x, dots[m][4]);
                dots[m][5] = fmaf(a, w1.y, dots[m][5]);
                dots[m][6] = fmaf(a, w1.z, dots[m][6]);
                dots[m][7] = fmaf(a, w1.w, dots[m][7]);
            }
        }
    }
    if (qu != 0){
        #pragma unroll
        for (int m = 0; m < 3; m++)
            #pragma unroll
            for (int e = 0; e < 8; e++) pd[qu-1][tok][m*8+e] = dots[m][e];
    }
    __syncthreads();
    if (qu == 0){
        #pragma unroll
        for (int qq = 0; qq < 3; qq++)
            #pragma unroll
            for (int m = 0; m < 3; m++)
                #pragma unroll
                for (int e = 0; e < 8; e++) dots[m][e] += pd[qq][tok][m*8+e];

        int lab = label[n];
        #pragma unroll
        for (int m = 0; m < 3; m++){
            float ss = ssbuf[(0*3+m)*(size_t)NTOK + n] + ssbuf[(1*3+m)*(size_t)NTOK + n];
            float scale = expf(fminf(gf.tp[m][0], LOG100));
            float inv = scale / (sqrtf(ss) + 1e-12f);
            float l8[8], mx = -1e30f;
            #pragma unroll
            for (int e = 0; e < 8; e++){
                l8[e] = (dots[m][e] + bd3[m*8+e]) * inv;
                mx = fmaxf(mx, l8[e]);
            }
            float g[8], s = 0.f;
            #pragma unroll
            for (int e = 0; e < 8; e++){ g[e] = expf(l8[e] - mx); s += g[e]; }
            #pragma unroll
            for (int e = 0; e < 8; e++) g[e] /= s;
            int e0 = 0; float b0 = g[0];
            #pragma unroll
            for (int e = 1; e < 8; e++) if (g[e] > b0){ b0 = g[e]; e0 = e; }
            int e1 = (e0 == 0) ? 1 : 0; float b1v = g[e1];
            #pragma unroll
            for (int e = 0; e < 8; e++) if (e != e0 && g[e] > b1v){ b1v = g[e]; e1 = e; }
            float maskv = (m == 0) ? 1.f : ((lab == m - 1) ? 1.f : 0.f);
            float s2 = b0 + b1v + 1e-9f;
            size_t base = (size_t)m * NSLOT + 2*(size_t)n;
            gw3[base]   = b0 / s2 * maskv;
            gw3[base+1] = b1v / s2 * maskv;
            idx3[base]   = e0;
            idx3[base+1] = e1;
        }
    }
}

// ---------- transposed-output bf16 MFMA GEMM core, 128x128, BK=32 (8192 shorts LDS) ----------
template<int BGATHER, int OMODE>
__device__ __forceinline__
void gemm_core_t(short* As, short* Bs,
                 const unsigned short* __restrict__ AT, const unsigned short* __restrict__ Bv,
                 const float* __restrict__ bias, void* __restrict__ Cout,
                 int Kd, int Mld, int row0, int col0, int limitN,
                 const int* __restrict__ rowidx, const int* __restrict__ otok,
                 const float* __restrict__ gs)
{
    const int t = threadIdx.x;
    const int w = t >> 6, l = t & 63;
    const int qrow = l >> 2;
    const int kc = (l & 3) * 8;

    long arowg[2], browg[2];
    #pragma unroll
    for (int q = 0; q < 2; q++){
        arowg[q] = (long)(row0 + w*32 + q*16 + qrow) * Kd;
        int s = col0 + w*32 + q*16 + qrow;
        int gi = s;
        if (BGATHER) gi = (s < limitN) ? rowidx[s] : 0;
        browg[q] = (long)gi * Kd;
    }

    const int wm = (w >> 1) * 64, wn = (w & 1) * 64;
    const int fr = l & 15, fk = l >> 4;
    const int koff = fk * 8, fk4 = fk * 4;

    f32x4 acc[4][4];
    #pragma unroll
    for (int i = 0; i < 4; i++)
        #pragma unroll
        for (int j = 0; j < 4; j++) acc[i][j] = (f32x4){0.f, 0.f, 0.f, 0.f};

    for (int k0 = 0; k0 < Kd; k0 += 32){
        __syncthreads();
        #pragma unroll
        for (int q = 0; q < 2; q++) gload16(AT + arowg[q] + k0 + kc, As + w*1024 + q*512);
        #pragma unroll
        for (int q = 0; q < 2; q++) gload16(Bv + browg[q] + k0 + kc, Bs + w*1024 + q*512);
        __syncthreads();
        bf16x8 af[4], bfv[4];
        #pragma unroll
        for (int i = 0; i < 4; i++) af[i]  = *(const bf16x8*)&As[(wm + i*16 + fr)*32 + koff];
        #pragma unroll
        for (int j = 0; j < 4; j++) bfv[j] = *(const bf16x8*)&Bs[(wn + j*16 + fr)*32 + koff];
        #pragma unroll
        for (int i = 0; i < 4; i++)
            #pragma unroll
            for (int j = 0; j < 4; j++)
                acc[i][j] = __builtin_amdgcn_mfma_f32_16x16x32_bf16(af[i], bfv[j], acc[i][j], 0, 0, 0);
    }

    #pragma unroll
    for (int i = 0; i < 4; i++){
        const int mc = row0 + wm + i*16 + fk4;
        float4 bb = *(const float4*)(bias + mc);
        #pragma unroll
        for (int j = 0; j < 4; j++){
            int s = col0 + wn + j*16 + fr;
            if (s < limitN){
                if (OMODE == 1){
                    ushort4 u;
                    u.x = f2bf(fmaxf(acc[i][j][0] + bb.x, 0.f));
                    u.y = f2bf(fmaxf(acc[i][j][1] + bb.y, 0.f));
                    u.z = f2bf(fmaxf(acc[i][j][2] + bb.z, 0.f));
                    u.w = f2bf(fmaxf(acc[i][j][3] + bb.w, 0.f));
                    *(ushort4*)((unsigned short*)Cout + (long)s * Mld + mc) = u;
                } else {
                    int tk = otok[s];
                    float g = gs[s];
                    float* op = (float*)Cout + (long)tk * Mld + mc;
                    float4 c = *(const float4*)op;
                    c.x += g * (acc[i][j][0] + bb.x);
                    c.y += g * (acc[i][j][1] + bb.y);
                    c.z += g * (acc[i][j][2] + bb.z);
                    c.w += g * (acc[i][j][3] + bb.w);
                    *(float4*)op = c;
                }
            }
        }
    }
}

// ---------- y-GEMM core: 64 feat x 128 slots, BK=32 (6144 shorts LDS) ----------
// Identical tile/accumulation order to the old BK=64 version (k ascends), half the LDS.
__device__ __forceinline__
void gemm_core_y32(short* lds,
                   const unsigned short* __restrict__ AT, const unsigned short* __restrict__ Bv,
                   const float* __restrict__ bias, float* __restrict__ out,
                   int row0, int col0, int limitN,
                   const int* __restrict__ otok, const float* __restrict__ gs)
{
    short* As = lds;          // 2048 shorts: [64][32]
    short* Bs = lds + 2048;   // 4096 shorts: [128][32]
    const int t = threadIdx.x, w = t >> 6, l = t & 63;
    const int seg = (l & 3) * 8;

    const long arow = (long)(row0 + w*16 + (l >> 2)) * HDIM;
    long brow[2];
    #pragma unroll
    for (int hh = 0; hh < 2; hh++)
        brow[hh] = (long)(col0 + w*32 + hh*16 + (l >> 2)) * HDIM;

    const int wm = (w >> 1) * 32, wn = (w & 1) * 64;
    const int fr = l & 15, fk = l >> 4;
    const int koff = fk * 8, fk4 = fk * 4;

    f32x4 acc[2][4];
    #pragma unroll
    for (int i = 0; i < 2; i++)
        #pragma unroll
        for (int j = 0; j < 4; j++) acc[i][j] = (f32x4){0.f, 0.f, 0.f, 0.f};

    for (int k0 = 0; k0 < HDIM; k0 += 32){
        __syncthreads();
        gload16(AT + arow + k0 + seg, As + w*512);
        #pragma unroll
        for (int hh = 0; hh < 2; hh++)
            gload16(Bv + brow[hh] + k0 + seg, Bs + w*1024 + hh*512);
        __syncthreads();
        bf16x8 af[2], bfv[4];
        #pragma unroll
        for (int i = 0; i < 2; i++)
            af[i] = *(const bf16x8*)&As[(wm + i*16 + fr)*32 + koff];
        #pragma unroll
        for (int j = 0; j < 4; j++)
            bfv[j] = *(const bf16x8*)&Bs[(wn + j*16 + fr)*32 + koff];
        #pragma unroll
        for (int i = 0; i < 2; i++)
            #pragma unroll
            for (int j = 0; j < 4; j++)
                acc[i][j] = __builtin_amdgcn_mfma_f32_16x16x32_bf16(af[i], bfv[j], acc[i][j], 0, 0, 0);
    }

    #pragma unroll
    for (int i = 0; i < 2; i++){
        const int mc = row0 + wm + i*16 + fk4;
        float4 bb = *(const float4*)(bias + mc);
        #pragma unroll
        for (int j = 0; j < 4; j++){
            int s = col0 + wn + j*16 + fr;
            if (s < limitN){
                int tk = otok[s];
                float g = gs[s];
                float* op = out + (long)tk * DDIM + mc;
                float4 c = *(const float4*)op;
                c.x += g * (acc[i][j][0] + bb.x);
                c.y += g * (acc[i][j][1] + bb.y);
                c.z += g * (acc[i][j][2] + bb.z);
                c.w += g * (acc[i][j][3] + bb.w);
                *(float4*)op = c;
            }
        }
    }
}

// ---------- serial GEMM (lowest tier) ----------
template<int BGATHER, int OMODE>
__global__ __launch_bounds__(256)
void mgemm3_k(const unsigned short* __restrict__ AT, const unsigned short* __restrict__ Bv,
              const float* __restrict__ bias, void* __restrict__ Cout,
              int Kd, int Mld,
              const int* __restrict__ rowidx, const int* __restrict__ otok,
              const float* __restrict__ gs, const int* __restrict__ cntp, int cnti)
{
    __shared__ __align__(16) short As[128*32];
    __shared__ __align__(16) short Bs[128*32];
    int limit = cntp[cnti]; if (limit > CAP) limit = CAP;
    int row0 = blockIdx.x * 128, col0 = blockIdx.y * 128;
    if (col0 >= limit) return;
    gemm_core_t<BGATHER, OMODE>(As, Bs, AT, Bv, bias, Cout, Kd, Mld,
                                row0, col0, limit, rowidx, otok, gs);
}

// ---------- cross-model pipelined FFN, 16KB LDS (10 blocks/CU) ----------
// grid (128,16): by 0..7 h(ge) BK32 128-feat blocks; by 8..15 y32(ge-1) 64-feat slices
struct FfnP { const float* b1[3]; const float* b2[3]; };
__global__ __launch_bounds__(256)
void ffnA_k(const unsigned short* __restrict__ xb,
            const unsigned short* __restrict__ W1T3, const unsigned short* __restrict__ W2T3,
            FfnP fp, unsigned short* __restrict__ h0, unsigned short* __restrict__ h1,
            float* __restrict__ out,
            const int* __restrict__ tok3, const float* __restrict__ gslot3,
            const int* __restrict__ cntk3, int ge)
{
    __shared__ __align__(16) short lds[8192];   // 16KB -> 10 blocks/CU
    const int bx = blockIdx.x, by = blockIdx.y;
    const int col0 = bx * 128;
    if (by < 8){
        if (ge >= 24) return;
        int m = ge >> 3, e = ge & 7;
        int limit = cntk3[m*16 + e]; if (limit > CAP) limit = CAP;
        if (col0 >= limit) return;
        unsigned short* hd = (ge & 1) ? h1 : h0;
        gemm_core_t<1, 1>(lds, lds + 4096,
                          W1T3 + ((size_t)(m*8+e))*HDIM*DDIM, xb, fp.b1[m] + (size_t)e*HDIM,
                          hd, DDIM, HDIM, by*128, col0, limit,
                          tok3 + ((size_t)m*NEXP + e)*CAP, nullptr, nullptr);
    } else {
        int gy = ge - 1; if (gy < 0) return;
        int m = gy >> 3, e = gy & 7;
        int limit = cntk3[m*16 + e]; if (limit > CAP) limit = CAP;
        if (col0 >= limit) return;
        const unsigned short* hs = (gy & 1) ? h1 : h0;
        gemm_core_y32(lds, W2T3 + ((size_t)(m*8+e))*DDIM*HDIM, hs, fp.b2[m] + (size_t)e*DDIM,
                      out, (by-8)*64, col0, limit,
                      tok3 + ((size_t)m*NEXP + e)*CAP, gslot3 + ((size_t)m*NEXP + e)*CAP);
    }
}

// ---------- paired-domain FFN step (m1 and m2 together; disjoint token sets) ----------
// grid (128,32): by 0..7 h(m1,s); 8..15 h(m2,s); 16..23 y(m1,s-1) [or y(m0,7) at s=0]; 24..31 y(m2,s-1)
__global__ __launch_bounds__(256)
void ffnD_k(const unsigned short* __restrict__ xb,
            const unsigned short* __restrict__ W1T3, const unsigned short* __restrict__ W2T3,
            FfnP fp, unsigned short* __restrict__ h0, unsigned short* __restrict__ h1,
            unsigned short* __restrict__ h2, unsigned short* __restrict__ h3,
            float* __restrict__ out,
            const int* __restrict__ tok3, const float* __restrict__ gslot3,
            const int* __restrict__ cntk3, int s)
{
    __shared__ __align__(16) short lds[8192];   // 16KB -> 10 blocks/CU
    const int bx = blockIdx.x, by = blockIdx.y;
    const int col0 = bx * 128;
    if (by < 16){
        if (s >= 8) return;
        int m = (by < 8) ? 1 : 2;
        int g = m*NEXP + s;
        int limit = cntk3[m*16 + s]; if (limit > CAP) limit = CAP;
        if (col0 >= limit) return;
        unsigned short* hd = (m == 1) ? ((s & 1) ? h1 : h0) : ((s & 1) ? h3 : h2);
        gemm_core_t<1, 1>(lds, lds + 4096,
                          W1T3 + (size_t)g*HDIM*DDIM, xb, fp.b1[m] + (size_t)s*HDIM,
                          hd, DDIM, HDIM, (by & 7)*128, col0, limit,
                          tok3 + (size_t)g*CAP, nullptr, nullptr);
    } else {
        int m, e; const unsigned short* hs_;
        if (s == 0){
            if (by >= 24) return;          // only y(m0,7) at s=0
            m = 0; e = 7; hs_ = h1;        // m0 e7 parity 1 -> h1
        } else {
            m = (by < 24) ? 1 : 2;
            e = s - 1;
            hs_ = (m == 1) ? ((e & 1) ? h1 : h0) : ((e & 1) ? h3 : h2);
        }
        int g = m*NEXP + e;
        int limit = cntk3[m*16 + e]; if (limit > CAP) limit = CAP;
        if (col0 >= limit) return;
        gemm_core_y32(lds, W2T3 + (size_t)g*DDIM*HDIM, hs_, fp.b2[m] + (size_t)e*DDIM,
                      out, ((by - 16) & 7)*64, col0, limit,
                      tok3 + (size_t)g*CAP, gslot3 + (size_t)g*CAP);
    }
}

// ---------- per-model pipelined FFN (lower tier) ----------
__global__ __launch_bounds__(256)
void ffnB_k(const unsigned short* __restrict__ xb,
            const unsigned short* __restrict__ W1T, const float* __restrict__ b1,
            const unsigned short* __restrict__ W2T, const float* __restrict__ b2,
            unsigned short* __restrict__ h0, unsigned short* __restrict__ h1,
            float* __restrict__ out,
            const int* __restrict__ tok, const float* __restrict__ gslot,
            const int* __restrict__ cntk, int eh)
{
    __shared__ __align__(16) short lds[8192];
    const int bx = blockIdx.x, by = blockIdx.y;
    const int col0 = bx * 128;
    if (by < 8){
        if (eh > 7) return;
        int limit = cntk[eh]; if (limit > CAP) limit = CAP;
        if (col0 >= limit) return;
        unsigned short* hd = (eh & 1) ? h1 : h0;
        gemm_core_t<1, 1>(lds, lds + 4096,
                          W1T + (size_t)eh*HDIM*DDIM, xb, b1 + (size_t)eh*HDIM,
                          hd, DDIM, HDIM, by*128, col0, limit,
                          tok + (size_t)eh*CAP, nullptr, nullptr);
    } else {
        int ey = eh - 1; if (ey < 0) return;
        int limit = cntk[ey]; if (limit > CAP) limit = CAP;
        if (col0 >= limit) return;
        const unsigned short* hs = (ey & 1) ? h1 : h0;
        gemm_core_y32(lds, W2T + (size_t)ey*DDIM*HDIM, hs, b2 + (size_t)ey*DDIM,
                      out, (by-8)*64, col0, limit,
                      tok + (size_t)ey*CAP, gslot + (size_t)ey*CAP);
    }
}

// ---------- ranking (batched over 3 models) ----------
__global__ __launch_bounds__(1024)
void rank_count3_k(const int* __restrict__ idx3, const int* __restrict__ label,
                   int* __restrict__ bcnt3)
{
    __shared__ int c[NEXP];
    const int m = blockIdx.y;
    const int* idx = idx3 + (size_t)m * NSLOT;
    int t = threadIdx.x;
    if (t < NEXP) c[t] = 0;
    __syncthreads();
    int s = blockIdx.x * 1024 + t;
    int n = s >> 1;
    int e = idx[s];
    bool valid = (m == 0) || (label[n] == m - 1);
    if (valid) atomicAdd(&c[e], 1);
    __syncthreads();
    if (t < NEXP) bcnt3[((size_t)m*128 + blockIdx.x)*NEXP + t] = c[t];
}

__global__ void rank_scan3_k(const int* __restrict__ bcnt3, int* __restrict__ boff3,
                             int* __restrict__ cntk3)
{
    int m = blockIdx.x, e = threadIdx.x;
    if (e < NEXP){
        int run = 0;
        for (int b = 0; b < NSLOT/1024; b++){
            boff3[((size_t)m*128 + b)*NEXP + e] = run;
            run += bcnt3[((size_t)m*128 + b)*NEXP + e];
        }
        cntk3[m*16 + e] = run < CAP ? run : CAP;
    }
}

__global__ __launch_bounds__(1024)
void rank_assign3_k(const int* __restrict__ idx3, const int* __restrict__ label,
                    const int* __restrict__ boff3, const float* __restrict__ gw3,
                    const float* __restrict__ dscale,
                    int* __restrict__ tok3, float* __restrict__ gs3)
{
    __shared__ int wcnt[16][NEXP];
    __shared__ int woff[16][NEXP];
    const int m = blockIdx.y;
    const int* idx = idx3 + (size_t)m * NSLOT;
    const float* gw = gw3 + (size_t)m * NSLOT;
    int t = threadIdx.x;
    int s = blockIdx.x * 1024 + t;
    int n = s >> 1;
    int e = idx[s];
    bool valid = (m == 0) || (label[n] == m - 1);
    int w = t >> 6, lane = t & 63;
    unsigned long long lt = (lane == 0) ? 0ull : ((1ull << lane) - 1ull);
    int myrank = 0;
    #pragma unroll
    for (int ei = 0; ei < NEXP; ei++){
        unsigned long long bal = __ballot(valid && (e == ei));
        if (ei == e) myrank = __popcll(bal & lt);
        if (lane == 0) wcnt[w][ei] = __popcll(bal);
    }
    __syncthreads();
    if (t < NEXP){
        int run = boff3[((size_t)m*128 + blockIdx.x)*NEXP + t];
        for (int w2 = 0; w2 < 16; w2++){
            woff[w2][t] = run;
            run += wcnt[w2][t];
        }
    }
    __syncthreads();
    int pos = woff[w][e] + myrank;
    bool keep = valid && (pos < CAP);
    if (keep){
        float scale = (m > 0) ? dscale[0] : 1.f;
        tok3[((size_t)m*NEXP + e)*CAP + pos] = n;
        gs3[((size_t)m*NEXP + e)*CAP + pos] = gw[s] * scale;
    }
}

extern "C" void kernel_launch(void* const* d_in, const int* in_sizes, int n_in,
                              void* d_out, int out_size, void* d_ws, size_t ws_size,
                              hipStream_t stream)
{
    (void)in_sizes; (void)n_in; (void)out_size;
    const float* x      = (const float*)d_in[0];
    const int*   label  = (const int*)  d_in[1];
    const float* dscale = (const float*)d_in[2];
    float* out = (float*)d_out;

    const size_t XB  = (size_t)NTOK * DDIM * 2;            // 64MB
    const size_t HS  = (size_t)CAP * HDIM * 2;             // 32MB
    const size_t WPT = (size_t)3 * PROJ * DDIM * 2;        // 768KB
    const size_t SS  = (size_t)2 * 3 * NTOK * 4;           // 1.5MB
    const size_t WN  = (size_t)3 * DDIM * 8 * 4;           // 48KB
    const size_t SMALL = WPT + SS + WN + 256 +
                         (size_t)3*PROJ*NEXP*4 +
                         (size_t)3*NSLOT*4*2 +
                         (size_t)3*NEXP*CAP*4*2 +
                         (size_t)3*128*NEXP*4*2 + 256;
    const size_t W12A = (size_t)2 * 3 * NEXP * DDIM * HDIM * 2;  // 48MB
    const size_t W12B = (size_t)2 * NEXP * DDIM * HDIM * 2;      // 16MB
    const size_t common = XB + HS + SMALL;                       // includes h0

    int tier;
    if      (ws_size >= common + 3*HS + W12A) tier = 0;   // paired-domain pipeline
    else if (ws_size >= common + HS + W12A)   tier = 1;   // cross-model pipeline
    else if (ws_size >= common + HS + W12B)   tier = 2;   // per-model pipelined
    else if (ws_size >= common + W12B)        tier = 3;   // per-model serial
    else return;  // clean failure, not a fault

    char* p = (char*)d_ws;
    unsigned short* xb   = (unsigned short*)p; p += XB;
    unsigned short* h0   = (unsigned short*)p; p += HS;
    unsigned short* WpT3 = (unsigned short*)p; p += WPT;
    float* ssbuf = (float*)p;  p += SS;
    float* Wn3   = (float*)p;  p += WN;
    float* bd3   = (float*)p;  p += 256;
    float* simn3 = (float*)p;  p += (size_t)3*PROJ*NEXP*4;
    int*   idx3  = (int*)p;    p += (size_t)3*NSLOT*4;
    float* gw3   = (float*)p;  p += (size_t)3*NSLOT*4;
    int*   tok3  = (int*)p;    p += (size_t)3*NEXP*CAP*4;
    float* gslot3= (float*)p;  p += (size_t)3*NEXP*CAP*4;
    int*   bcnt3 = (int*)p;    p += (size_t)3*128*NEXP*4;
    int*   boff3 = (int*)p;    p += (size_t)3*128*NEXP*4;
    int*   cntk3 = (int*)p;    p += 256;
    unsigned short* h1 = nullptr;
    unsigned short* h2 = nullptr;
    unsigned short* h3 = nullptr;
    if (tier <= 2){ h1 = (unsigned short*)p; p += HS; }
    if (tier == 0){ h2 = (unsigned short*)p; p += HS; h3 = (unsigned short*)p; p += HS; }
    unsigned short* Wbuf = (unsigned short*)p;

    SimArgs sa; TpArgs ta; WprodArgs wa; PssArgs pa; GfArgs gf; W12P wp; FfnP fp;
    for (int m = 0; m < 3; m++){
        ta.Wp[m] = (const float*)d_in[3 + 8*m + 0];
        wa.Wp[m] = ta.Wp[m];
        wa.bp[m] = (const float*)d_in[3 + 8*m + 1];
        pa.bp[m] = wa.bp[m];
        sa.sim[m] = (const float*)d_in[3 + 8*m + 2];
        gf.tp[m] = (const float*)d_in[3 + 8*m + 3];
        wp.W1[m] = (const float*)d_in[3 + 8*m + 4];
        fp.b1[m] = (const float*)d_in[3 + 8*m + 5];
        wp.W2[m] = (const float*)d_in[3 + 8*m + 6];
        fp.b2[m] = (const float*)d_in[3 + 8*m + 7];
    }

    // ---- prep + gate ----
    init_k<<<dim3(NTOK*DDIM/4/256), dim3(256), 0, stream>>>(
        (const float4*)x, (ushort4*)xb, (float4*)out);
    simn3_k<<<dim3(3), dim3(256), 0, stream>>>(sa, simn3);
    transWp_k<<<dim3(PROJ/32, DDIM/32, 3), dim3(32,8), 0, stream>>>(ta, WpT3);
    wprod_k<<<dim3(3), dim3(256), 0, stream>>>(wa, simn3, Wn3, bd3);
    pss_k<<<dim3(2, NTOK/128, 3), dim3(256), 0, stream>>>(WpT3, xb, pa, ssbuf);
    gatefin3_k<<<dim3(NTOK/64), dim3(256), 0, stream>>>(
        x, label, Wn3, bd3, ssbuf, gf, idx3, gw3);

    // ---- ranking ----
    rank_count3_k<<<dim3(NSLOT/1024, 3), dim3(1024), 0, stream>>>(idx3, label, bcnt3);
    rank_scan3_k<<<dim3(3), dim3(64), 0, stream>>>(bcnt3, boff3, cntk3);
    rank_assign3_k<<<dim3(NSLOT/1024, 3), dim3(1024), 0, stream>>>(
        idx3, label, boff3, gw3, dscale, tok3, gslot3);

    // ---- FFN ----
    if (tier <= 1){
        unsigned short* W1T3 = Wbuf;
        unsigned short* W2T3 = Wbuf + (size_t)3*NEXP*DDIM*HDIM;
        transW12all_k<<<dim3(32, 32, 48), dim3(32,8), 0, stream>>>(wp, W1T3, W2T3);
        if (tier == 0){
            // m0 phase: 8 balanced dispatches (h e + y e-1)
            for (int ge = 0; ge < 8; ge++)
                ffnA_k<<<dim3(128, 16), 256, 0, stream>>>(
                    xb, W1T3, W2T3, fp, h0, h1, out, tok3, gslot3, cntk3, ge);
            // paired domain phase: 9 dispatches; s=0 also carries y(m0,7)
            for (int s = 0; s <= 8; s++)
                ffnD_k<<<dim3(128, 32), 256, 0, stream>>>(
                    xb, W1T3, W2T3, fp, h0, h1, h2, h3, out, tok3, gslot3, cntk3, s);
        } else {
            for (int ge = 0; ge <= 24; ge++)
                ffnA_k<<<dim3(128, 16), 256, 0, stream>>>(
                    xb, W1T3, W2T3, fp, h0, h1, out, tok3, gslot3, cntk3, ge);
        }
    } else {
        unsigned short* W1T = Wbuf;
        unsigned short* W2T = Wbuf + (size_t)NEXP*DDIM*HDIM;
        for (int m = 0; m < 3; m++){
            trans2_k<<<dim3(32, 32, 16), dim3(32,8), 0, stream>>>(wp.W1[m], wp.W2[m], W1T, W2T);
            const int* tokm = tok3 + (size_t)m*NEXP*CAP;
            const float* gsm = gslot3 + (size_t)m*NEXP*CAP;
            const int* cntm = cntk3 + m*16;
            if (tier == 2){
                for (int eh = 0; eh <= 8; eh++)
                    ffnB_k<<<dim3(128, 16), 256, 0, stream>>>(
                        xb, W1T, fp.b1[m], W2T, fp.b2[m], h0, h1, out, tokm, gsm, cntm, eh);
            } else {
                for (int e = 0; e < NEXP; e++){
                    mgemm3_k<1, 1><<<dim3(HDIM/128, CAP/128), 256, 0, stream>>>(
                        W1T + (size_t)e*HDIM*DDIM, xb, fp.b1[m] + (size_t)e*HDIM, h0,
                        DDIM, HDIM, tokm + (size_t)e*CAP, nullptr, nullptr, cntm, e);
                    mgemm3_k<0, 3><<<dim3(DDIM/128, CAP/128), 256, 0, stream>>>(
                        W2T + (size_t)e*DDIM*HDIM, h0, fp.b2[m] + (size_t)e*DDIM, out,
                        HDIM, DDIM, nullptr, tokm + (size_t)e*CAP, gsm + (size_t)e*CAP, cntm, e);
                }
            }
        }
    }
}

// Round 14
// 1738.577 us; speedup vs baseline: 1.0072x; 1.0072x over previous
//
#include <hip/hip_runtime.h>

#define NTOK 65536
#define DDIM 512
#define HDIM 1024
#define NEXP 8
#define PROJ 256
#define CAP  16384
#define NSLOT (2*NTOK)
#define LOG100 4.605170185988091f

typedef __attribute__((ext_vector_type(8))) short bf16x8;
typedef __attribute__((ext_vector_type(4))) short short4v;
typedef __attribute__((ext_vector_type(4))) float f32x4;

// ---------- helpers ----------
__device__ inline float bf2f(unsigned short u){
    union { float f; unsigned int i; } c; c.i = ((unsigned int)u) << 16; return c.f;
}
__device__ inline unsigned short f2bf(float f){
    union { float f; unsigned int i; } c; c.f = f;
    unsigned int x = c.i;
    return (unsigned short)((x + 0x7fffu + ((x >> 16) & 1u)) >> 16); // RTNE
}
__device__ inline void gload16(const void* g, void* lds){
    __builtin_amdgcn_global_load_lds(
        (const __attribute__((address_space(1))) unsigned int*)g,
        (__attribute__((address_space(3))) unsigned int*)lds, 16, 0, 0);
}

// ---------- fused init: xb = bf16(x), out = 0 ----------
__global__ void init_k(const float4* __restrict__ x, ushort4* __restrict__ xb,
                       float4* __restrict__ out){
    long i = (long)blockIdx.x * 256 + threadIdx.x;
    float4 f = x[i];
    ushort4 u; u.x = f2bf(f.x); u.y = f2bf(f.y); u.z = f2bf(f.z); u.w = f2bf(f.w);
    xb[i] = u;
    out[i] = float4{0.f, 0.f, 0.f, 0.f};
}

// ---------- generic 32x32-tiled transpose+convert body ----------
__device__ inline void trans_body(const float* in, unsigned short* out, int R, int C){
    int rbase = blockIdx.y * 32, cbase = blockIdx.x * 32;
    if (rbase >= R || cbase >= C) return;
    __shared__ float tile[32][33];
    int tx = threadIdx.x, ty = threadIdx.y;   // (32,8)
    #pragma unroll
    for (int i = 0; i < 4; i++)
        tile[ty + i*8][tx] = in[(long)(rbase + ty + i*8) * C + cbase + tx];
    __syncthreads();
    #pragma unroll
    for (int i = 0; i < 4; i++)
        out[(long)(cbase + ty + i*8) * R + rbase + tx] = f2bf(tile[tx][ty + i*8]);
}

// per-model W1/W2 transpose (lower tiers)
__global__ __launch_bounds__(256)
void trans2_k(const float* __restrict__ W1, const float* __restrict__ W2,
              unsigned short* __restrict__ W1T, unsigned short* __restrict__ W2T)
{
    int z = blockIdx.z;
    if (z < 8) trans_body(W1 + (size_t)z*DDIM*HDIM, W1T + (size_t)z*DDIM*HDIM, DDIM, HDIM);
    else       trans_body(W2 + (size_t)(z-8)*DDIM*HDIM, W2T + (size_t)(z-8)*DDIM*HDIM, HDIM, DDIM);
}

// all-model W1/W2 transpose
struct W12P { const float* W1[3]; const float* W2[3]; };
__global__ __launch_bounds__(256)
void transW12all_k(W12P wp, unsigned short* __restrict__ W1T3, unsigned short* __restrict__ W2T3)
{
    int z = blockIdx.z, m = z >> 4, piece = z & 15;
    if (piece < 8)
        trans_body(wp.W1[m] + (size_t)piece*DDIM*HDIM,
                   W1T3 + ((size_t)m*8 + piece)*DDIM*HDIM, DDIM, HDIM);
    else
        trans_body(wp.W2[m] + (size_t)(piece-8)*DDIM*HDIM,
                   W2T3 + ((size_t)m*8 + piece-8)*DDIM*HDIM, HDIM, DDIM);
}

// Wp transpose: [512][256] f32 -> [256][512] bf16, per model
struct TpArgs { const float* Wp[3]; };
__global__ __launch_bounds__(256)
void transWp_k(TpArgs ta, unsigned short* __restrict__ WpT3)
{
    int m = blockIdx.z;
    trans_body(ta.Wp[m], WpT3 + (size_t)m*PROJ*DDIM, DDIM, PROJ);
}

// ---------- normalize sim columns ----------
struct SimArgs { const float* sim[3]; };
__global__ void simn3_k(SimArgs sa, float* __restrict__ simn3){
    __shared__ float red[256];
    const float* sim = sa.sim[blockIdx.x];
    float* simn = simn3 + (size_t)blockIdx.x * PROJ * NEXP;
    int j = threadIdx.x;
    for (int e = 0; e < NEXP; e++){
        float v = sim[j*NEXP + e];
        red[j] = v*v;
        __syncthreads();
        for (int s = 128; s > 0; s >>= 1){
            if (j < s) red[j] += red[j + s];
            __syncthreads();
        }
        float nrm = sqrtf(red[0]) + 1e-12f;
        __syncthreads();
        simn[j*NEXP + e] = v / nrm;
    }
}

// ---------- W' = Wp @ simn (fp32), bd = bp @ simn ----------
struct WprodArgs { const float* Wp[3]; const float* bp[3]; };
__global__ __launch_bounds__(256)
void wprod_k(WprodArgs wa, const float* __restrict__ simn3,
             float* __restrict__ Wn3, float* __restrict__ bd3)
{
    int m = blockIdx.x;
    __shared__ float Sn[PROJ*NEXP];
    const float* Wp = wa.Wp[m];
    int t = threadIdx.x;
    for (int i = t; i < PROJ*NEXP; i += 256) Sn[i] = simn3[(size_t)m*PROJ*NEXP + i];
    __syncthreads();
    for (int r = t; r < DDIM; r += 256){
        float d[8];
        #pragma unroll
        for (int e = 0; e < 8; e++) d[e] = 0.f;
        for (int p = 0; p < PROJ; p++){
            float w = Wp[(size_t)r*PROJ + p];
            #pragma unroll
            for (int e = 0; e < 8; e++) d[e] = fmaf(w, Sn[p*8+e], d[e]);
        }
        #pragma unroll
        for (int e = 0; e < 8; e++) Wn3[((size_t)m*DDIM + r)*8 + e] = d[e];
    }
    if (t < 8){
        float s = 0.f;
        for (int p = 0; p < PROJ; p++) s = fmaf(wa.bp[m][p], Sn[p*8+t], s);
        bd3[m*8 + t] = s;
    }
}

// ---------- pss: MFMA P-GEMM, epilogue = row-norm^2 only ----------
struct PssArgs { const float* bp[3]; };
__global__ __launch_bounds__(256)
void pss_k(const unsigned short* __restrict__ WpT3, const unsigned short* __restrict__ xb,
           PssArgs pa, float* __restrict__ ssbuf)
{
    __shared__ __align__(16) short As[128*32];
    __shared__ __align__(16) short Bs[128*32];
    __shared__ float ssl[2][128];
    const int m = blockIdx.z;
    const int row0 = blockIdx.x * 128;
    const int n0 = blockIdx.y * 128;
    const unsigned short* AT = WpT3 + (size_t)m * PROJ * DDIM;
    const float* bp = pa.bp[m];

    const int t = threadIdx.x, w = t >> 6, l = t & 63;
    const int qrow = l >> 2, kc = (l & 3) * 8;
    long arowg[2], browg[2];
    #pragma unroll
    for (int q = 0; q < 2; q++){
        arowg[q] = (long)(row0 + w*32 + q*16 + qrow) * DDIM;
        browg[q] = (long)(n0   + w*32 + q*16 + qrow) * DDIM;
    }
    const int wm = (w >> 1) * 64, wn = (w & 1) * 64;
    const int fr = l & 15, fk = l >> 4;
    const int koff = fk * 8, fk4 = fk * 4;

    f32x4 acc[4][4];
    #pragma unroll
    for (int i = 0; i < 4; i++)
        #pragma unroll
        for (int j = 0; j < 4; j++) acc[i][j] = (f32x4){0.f, 0.f, 0.f, 0.f};

    for (int k0 = 0; k0 < DDIM; k0 += 32){
        __syncthreads();
        #pragma unroll
        for (int q = 0; q < 2; q++) gload16(AT + arowg[q] + k0 + kc, As + w*1024 + q*512);
        #pragma unroll
        for (int q = 0; q < 2; q++) gload16(xb + browg[q] + k0 + kc, Bs + w*1024 + q*512);
        __syncthreads();
        bf16x8 af[4], bfv[4];
        #pragma unroll
        for (int i = 0; i < 4; i++) af[i]  = *(const bf16x8*)&As[(wm + i*16 + fr)*32 + koff];
        #pragma unroll
        for (int j = 0; j < 4; j++) bfv[j] = *(const bf16x8*)&Bs[(wn + j*16 + fr)*32 + koff];
        #pragma unroll
        for (int i = 0; i < 4; i++)
            #pragma unroll
            for (int j = 0; j < 4; j++)
                acc[i][j] = __builtin_amdgcn_mfma_f32_16x16x32_bf16(af[i], bfv[j], acc[i][j], 0, 0, 0);
    }

    float part[4];
    #pragma unroll
    for (int j = 0; j < 4; j++){
        float s = 0.f;
        #pragma unroll
        for (int i = 0; i < 4; i++){
            int mc = row0 + wm + i*16 + fk4;
            float4 bb = *(const float4*)(bp + mc);
            float v0 = acc[i][j][0] + bb.x;
            float v1 = acc[i][j][1] + bb.y;
            float v2 = acc[i][j][2] + bb.z;
            float v3 = acc[i][j][3] + bb.w;
            s += v0*v0 + v1*v1 + v2*v2 + v3*v3;
        }
        s += __shfl_xor(s, 16, 64);
        s += __shfl_xor(s, 32, 64);
        part[j] = s;
    }
    if (fk == 0){
        #pragma unroll
        for (int j = 0; j < 4; j++) ssl[w >> 1][wn + j*16 + fr] = part[j];
    }
    __syncthreads();
    if (t < 128)
        ssbuf[((size_t)blockIdx.x*3 + m)*NTOK + n0 + t] = ssl[0][t] + ssl[1][t];
}

// ---------- gatefin3: k-split GEMV, wave-uniform W s_loads ----------
struct GfArgs { const float* tp[3]; };
__global__ __launch_bounds__(256)
void gatefin3_k(const float* __restrict__ x, const int* __restrict__ label,
                const float* __restrict__ Wn3, const float* __restrict__ bd3,
                const float* __restrict__ ssbuf, GfArgs gf,
                int* __restrict__ idx3, float* __restrict__ gw3)
{
    __shared__ float pd[3][64][26];
    const int t = threadIdx.x;
    const int tok = t & 63;
    const int qu = __builtin_amdgcn_readfirstlane(t >> 6);
    const int n = blockIdx.x * 64 + tok;

    float dots[3][8];
    #pragma unroll
    for (int m = 0; m < 3; m++)
        #pragma unroll
        for (int e = 0; e < 8; e++) dots[m][e] = 0.f;

    const float4* xp = (const float4*)(x + (size_t)n * DDIM + qu * 128);
    for (int c = 0; c < 8; c++){
        float4 xv[4];
        #pragma unroll
        for (int u = 0; u < 4; u++) xv[u] = xp[c*4 + u];
        #pragma unroll
        for (int kk = 0; kk < 16; kk++){
            float a = (kk & 2) ? ((kk & 1) ? xv[kk>>2].w : xv[kk>>2].z)
                               : ((kk & 1) ? xv[kk>>2].y : xv[kk>>2].x);
            int k = qu*128 + c*16 + kk;
            #pragma unroll
            for (int m = 0; m < 3; m++){
                const float* wr = Wn3 + ((size_t)m*DDIM + k)*8;
                float4 w0 = *(const float4*)wr;
                float4 w1 = *(const float4*)(wr + 4);
                dots[m][0] = fmaf(a, w0.x, dots[m][0]);
                dots[m][1] = fmaf(a, w0.y, dots[m][1]);
                dots[m][2] = fmaf(a, w0.z, dots[m][2]);
                dots[m][3] = fmaf(a, w0.w, dots[m][3]);
                dots[m][4] = fmaf(a, w1.x, dots[m][4]);
                dots[m][5] = fmaf(a, w1.y, dots[m][5]);
                dots[m][6] = fmaf(a, w1.z, dots[m][6]);
                dots[m][7] = fmaf(a, w1.w, dots[m][7]);
            }
        }
    }
    if (qu != 0){
        #pragma unroll
        for (int m = 0; m < 3; m++)
            #pragma unroll
            for (int e = 0; e < 8; e++) pd[qu-1][tok][m*8+e] = dots[m][e];
    }
    __syncthreads();
    if (qu == 0){
        #pragma unroll
        for (int qq = 0; qq < 3; qq++)
            #pragma unroll
            for (int m = 0; m < 3; m++)
                #pragma unroll
                for (int e = 0; e < 8; e++) dots[m][e] += pd[qq][tok][m*8+e];

        int lab = label[n];
        #pragma unroll
        for (int m = 0; m < 3; m++){
            float ss = ssbuf[(0*3+m)*(size_t)NTOK + n] + ssbuf[(1*3+m)*(size_t)NTOK + n];
            float scale = expf(fminf(gf.tp[m][0], LOG100));
            float inv = scale / (sqrtf(ss) + 1e-12f);
            float l8[8], mx = -1e30f;
            #pragma unroll
            for (int e = 0; e < 8; e++){
                l8[e] = (dots[m][e] + bd3[m*8+e]) * inv;
                mx = fmaxf(mx, l8[e]);
            }
            float g[8], s = 0.f;
            #pragma unroll
            for (int e = 0; e < 8; e++){ g[e] = expf(l8[e] - mx); s += g[e]; }
            #pragma unroll
            for (int e = 0; e < 8; e++) g[e] /= s;
            int e0 = 0; float b0 = g[0];
            #pragma unroll
            for (int e = 1; e < 8; e++) if (g[e] > b0){ b0 = g[e]; e0 = e; }
            int e1 = (e0 == 0) ? 1 : 0; float b1v = g[e1];
            #pragma unroll
            for (int e = 0; e < 8; e++) if (e != e0 && g[e] > b1v){ b1v = g[e]; e1 = e; }
            float maskv = (m == 0) ? 1.f : ((lab == m - 1) ? 1.f : 0.f);
            float s2 = b0 + b1v + 1e-9f;
            size_t base = (size_t)m * NSLOT + 2*(size_t)n;
            gw3[base]   = b0 / s2 * maskv;
            gw3[base+1] = b1v / s2 * maskv;
            idx3[base]   = e0;
            idx3[base+1] = e1;
        }
    }
}

// ---------- single-buffer 128x128 BK=32 core (serial tier only) ----------
template<int BGATHER, int OMODE>
__device__ __forceinline__
void gemm_core_t(short* As, short* Bs,
                 const unsigned short* __restrict__ AT, const unsigned short* __restrict__ Bv,
                 const float* __restrict__ bias, void* __restrict__ Cout,
                 int Kd, int Mld, int row0, int col0, int limitN,
                 const int* __restrict__ rowidx, const int* __restrict__ otok,
                 const float* __restrict__ gs)
{
    const int t = threadIdx.x;
    const int w = t >> 6, l = t & 63;
    const int qrow = l >> 2;
    const int kc = (l & 3) * 8;

    long arowg[2], browg[2];
    #pragma unroll
    for (int q = 0; q < 2; q++){
        arowg[q] = (long)(row0 + w*32 + q*16 + qrow) * Kd;
        int s = col0 + w*32 + q*16 + qrow;
        int gi = s;
        if (BGATHER) gi = (s < limitN) ? rowidx[s] : 0;
        browg[q] = (long)gi * Kd;
    }

    const int wm = (w >> 1) * 64, wn = (w & 1) * 64;
    const int fr = l & 15, fk = l >> 4;
    const int koff = fk * 8, fk4 = fk * 4;

    f32x4 acc[4][4];
    #pragma unroll
    for (int i = 0; i < 4; i++)
        #pragma unroll
        for (int j = 0; j < 4; j++) acc[i][j] = (f32x4){0.f, 0.f, 0.f, 0.f};

    for (int k0 = 0; k0 < Kd; k0 += 32){
        __syncthreads();
        #pragma unroll
        for (int q = 0; q < 2; q++) gload16(AT + arowg[q] + k0 + kc, As + w*1024 + q*512);
        #pragma unroll
        for (int q = 0; q < 2; q++) gload16(Bv + browg[q] + k0 + kc, Bs + w*1024 + q*512);
        __syncthreads();
        bf16x8 af[4], bfv[4];
        #pragma unroll
        for (int i = 0; i < 4; i++) af[i]  = *(const bf16x8*)&As[(wm + i*16 + fr)*32 + koff];
        #pragma unroll
        for (int j = 0; j < 4; j++) bfv[j] = *(const bf16x8*)&Bs[(wn + j*16 + fr)*32 + koff];
        #pragma unroll
        for (int i = 0; i < 4; i++)
            #pragma unroll
            for (int j = 0; j < 4; j++)
                acc[i][j] = __builtin_amdgcn_mfma_f32_16x16x32_bf16(af[i], bfv[j], acc[i][j], 0, 0, 0);
    }

    #pragma unroll
    for (int i = 0; i < 4; i++){
        const int mc = row0 + wm + i*16 + fk4;
        float4 bb = *(const float4*)(bias + mc);
        #pragma unroll
        for (int j = 0; j < 4; j++){
            int s = col0 + wn + j*16 + fr;
            if (s < limitN){
                if (OMODE == 1){
                    ushort4 u;
                    u.x = f2bf(fmaxf(acc[i][j][0] + bb.x, 0.f));
                    u.y = f2bf(fmaxf(acc[i][j][1] + bb.y, 0.f));
                    u.z = f2bf(fmaxf(acc[i][j][2] + bb.z, 0.f));
                    u.w = f2bf(fmaxf(acc[i][j][3] + bb.w, 0.f));
                    *(ushort4*)((unsigned short*)Cout + (long)s * Mld + mc) = u;
                } else {
                    int tk = otok[s];
                    float g = gs[s];
                    float* op = (float*)Cout + (long)tk * Mld + mc;
                    float4 c = *(const float4*)op;
                    c.x += g * (acc[i][j][0] + bb.x);
                    c.y += g * (acc[i][j][1] + bb.y);
                    c.z += g * (acc[i][j][2] + bb.z);
                    c.w += g * (acc[i][j][3] + bb.w);
                    *(float4*)op = c;
                }
            }
        }
    }
}

// ---------- 2-phase double-buffered 128x128 BK=32 core (32KB LDS) ----------
// LDS layout (shorts): As0 [0,4096) As1 [4096,8192) Bs0 [8192,12288) Bs1 [12288,16384)
template<int BGATHER, int OMODE>
__device__ __forceinline__
void gemm_core_t2(short* lds,
                  const unsigned short* __restrict__ AT, const unsigned short* __restrict__ Bv,
                  const float* __restrict__ bias, void* __restrict__ Cout,
                  int Kd, int Mld, int row0, int col0, int limitN,
                  const int* __restrict__ rowidx, const int* __restrict__ otok,
                  const float* __restrict__ gs)
{
    const int t = threadIdx.x;
    const int w = t >> 6, l = t & 63;
    const int qrow = l >> 2;
    const int kc = (l & 3) * 8;

    long arowg[2], browg[2];
    #pragma unroll
    for (int q = 0; q < 2; q++){
        arowg[q] = (long)(row0 + w*32 + q*16 + qrow) * Kd;
        int s = col0 + w*32 + q*16 + qrow;
        int gi = s;
        if (BGATHER) gi = (s < limitN) ? rowidx[s] : 0;
        browg[q] = (long)gi * Kd;
    }

    const int wm = (w >> 1) * 64, wn = (w & 1) * 64;
    const int fr = l & 15, fk = l >> 4;
    const int koff = fk * 8, fk4 = fk * 4;

    f32x4 acc[4][4];
    #pragma unroll
    for (int i = 0; i < 4; i++)
        #pragma unroll
        for (int j = 0; j < 4; j++) acc[i][j] = (f32x4){0.f, 0.f, 0.f, 0.f};

    const int nsteps = Kd >> 5;
    // prologue: stage step 0 into buffer 0
    #pragma unroll
    for (int q = 0; q < 2; q++) gload16(AT + arowg[q] + kc, lds + w*1024 + q*512);
    #pragma unroll
    for (int q = 0; q < 2; q++) gload16(Bv + browg[q] + kc, lds + 8192 + w*1024 + q*512);
    __syncthreads();

    for (int s = 0; s < nsteps; s++){
        const int cur = s & 1;
        // issue next tile's loads into the other buffer (before compute)
        if (s + 1 < nsteps){
            const int nxt = cur ^ 1;
            const int k = (s + 1) << 5;
            short* An = lds + nxt*4096;
            short* Bn = lds + 8192 + nxt*4096;
            #pragma unroll
            for (int q = 0; q < 2; q++) gload16(AT + arowg[q] + k + kc, An + w*1024 + q*512);
            #pragma unroll
            for (int q = 0; q < 2; q++) gload16(Bv + browg[q] + k + kc, Bn + w*1024 + q*512);
        }
        // compute current buffer
        short* Ac = lds + cur*4096;
        short* Bc = lds + 8192 + cur*4096;
        bf16x8 af[4], bfv[4];
        #pragma unroll
        for (int i = 0; i < 4; i++) af[i]  = *(const bf16x8*)&Ac[(wm + i*16 + fr)*32 + koff];
        #pragma unroll
        for (int j = 0; j < 4; j++) bfv[j] = *(const bf16x8*)&Bc[(wn + j*16 + fr)*32 + koff];
        #pragma unroll
        for (int i = 0; i < 4; i++)
            #pragma unroll
            for (int j = 0; j < 4; j++)
                acc[i][j] = __builtin_amdgcn_mfma_f32_16x16x32_bf16(af[i], bfv[j], acc[i][j], 0, 0, 0);
        __syncthreads();   // drains next-tile loads + all reads of current buffer
    }

    #pragma unroll
    for (int i = 0; i < 4; i++){
        const int mc = row0 + wm + i*16 + fk4;
        float4 bb = *(const float4*)(bias + mc);
        #pragma unroll
        for (int j = 0; j < 4; j++){
            int s = col0 + wn + j*16 + fr;
            if (s < limitN){
                if (OMODE == 1){
                    ushort4 u;
                    u.x = f2bf(fmaxf(acc[i][j][0] + bb.x, 0.f));
                    u.y = f2bf(fmaxf(acc[i][j][1] + bb.y, 0.f));
                    u.z = f2bf(fmaxf(acc[i][j][2] + bb.z, 0.f));
                    u.w = f2bf(fmaxf(acc[i][j][3] + bb.w, 0.f));
                    *(ushort4*)((unsigned short*)Cout + (long)s * Mld + mc) = u;
                } else {
                    int tk = otok[s];
                    float g = gs[s];
                    float* op = (float*)Cout + (long)tk * Mld + mc;
                    float4 c = *(const float4*)op;
                    c.x += g * (acc[i][j][0] + bb.x);
                    c.y += g * (acc[i][j][1] + bb.y);
                    c.z += g * (acc[i][j][2] + bb.z);
                    c.w += g * (acc[i][j][3] + bb.w);
                    *(float4*)op = c;
                }
            }
        }
    }
}

// ---------- 2-phase y-GEMM core: 64 feat x 128 slots, BK=32 (24KB LDS) ----------
// LDS layout (shorts): As0 [0,2048) As1 [2048,4096) Bs0 [4096,8192) Bs1 [8192,12288)
__device__ __forceinline__
void gemm_core_y2(short* lds,
                  const unsigned short* __restrict__ AT, const unsigned short* __restrict__ Bv,
                  const float* __restrict__ bias, float* __restrict__ out,
                  int row0, int col0, int limitN,
                  const int* __restrict__ otok, const float* __restrict__ gs)
{
    const int t = threadIdx.x, w = t >> 6, l = t & 63;
    const int seg = (l & 3) * 8;

    const long arow = (long)(row0 + w*16 + (l >> 2)) * HDIM;
    long brow[2];
    #pragma unroll
    for (int hh = 0; hh < 2; hh++)
        brow[hh] = (long)(col0 + w*32 + hh*16 + (l >> 2)) * HDIM;

    const int wm = (w >> 1) * 32, wn = (w & 1) * 64;
    const int fr = l & 15, fk = l >> 4;
    const int koff = fk * 8, fk4 = fk * 4;

    f32x4 acc[2][4];
    #pragma unroll
    for (int i = 0; i < 2; i++)
        #pragma unroll
        for (int j = 0; j < 4; j++) acc[i][j] = (f32x4){0.f, 0.f, 0.f, 0.f};

    const int nsteps = HDIM >> 5;   // 32
    // prologue: stage step 0 into buffer 0
    gload16(AT + arow + seg, lds + w*512);
    #pragma unroll
    for (int hh = 0; hh < 2; hh++)
        gload16(Bv + brow[hh] + seg, lds + 4096 + w*1024 + hh*512);
    __syncthreads();

    for (int s = 0; s < nsteps; s++){
        const int cur = s & 1;
        if (s + 1 < nsteps){
            const int nxt = cur ^ 1;
            const int k = (s + 1) << 5;
            gload16(AT + arow + k + seg, lds + nxt*2048 + w*512);
            #pragma unroll
            for (int hh = 0; hh < 2; hh++)
                gload16(Bv + brow[hh] + k + seg, lds + 4096 + nxt*4096 + w*1024 + hh*512);
        }
        short* Ac = lds + cur*2048;
        short* Bc = lds + 4096 + cur*4096;
        bf16x8 af[2], bfv[4];
        #pragma unroll
        for (int i = 0; i < 2; i++)
            af[i] = *(const bf16x8*)&Ac[(wm + i*16 + fr)*32 + koff];
        #pragma unroll
        for (int j = 0; j < 4; j++)
            bfv[j] = *(const bf16x8*)&Bc[(wn + j*16 + fr)*32 + koff];
        #pragma unroll
        for (int i = 0; i < 2; i++)
            #pragma unroll
            for (int j = 0; j < 4; j++)
                acc[i][j] = __builtin_amdgcn_mfma_f32_16x16x32_bf16(af[i], bfv[j], acc[i][j], 0, 0, 0);
        __syncthreads();
    }

    #pragma unroll
    for (int i = 0; i < 2; i++){
        const int mc = row0 + wm + i*16 + fk4;
        float4 bb = *(const float4*)(bias + mc);
        #pragma unroll
        for (int j = 0; j < 4; j++){
            int s = col0 + wn + j*16 + fr;
            if (s < limitN){
                int tk = otok[s];
                float g = gs[s];
                float* op = out + (long)tk * DDIM + mc;
                float4 c = *(const float4*)op;
                c.x += g * (acc[i][j][0] + bb.x);
                c.y += g * (acc[i][j][1] + bb.y);
                c.z += g * (acc[i][j][2] + bb.z);
                c.w += g * (acc[i][j][3] + bb.w);
                *(float4*)op = c;
            }
        }
    }
}

// ---------- serial GEMM (lowest tier) ----------
template<int BGATHER, int OMODE>
__global__ __launch_bounds__(256)
void mgemm3_k(const unsigned short* __restrict__ AT, const unsigned short* __restrict__ Bv,
              const float* __restrict__ bias, void* __restrict__ Cout,
              int Kd, int Mld,
              const int* __restrict__ rowidx, const int* __restrict__ otok,
              const float* __restrict__ gs, const int* __restrict__ cntp, int cnti)
{
    __shared__ __align__(16) short As[128*32];
    __shared__ __align__(16) short Bs[128*32];
    int limit = cntp[cnti]; if (limit > CAP) limit = CAP;
    int row0 = blockIdx.x * 128, col0 = blockIdx.y * 128;
    if (col0 >= limit) return;
    gemm_core_t<BGATHER, OMODE>(As, Bs, AT, Bv, bias, Cout, Kd, Mld,
                                row0, col0, limit, rowidx, otok, gs);
}

// ---------- cross-model pipelined FFN, 2-phase cores, 32KB LDS ----------
// grid (128,16): by 0..7 h(ge) 128-feat blocks; by 8..15 y(ge-1) 64-feat slices
struct FfnP { const float* b1[3]; const float* b2[3]; };
__global__ __launch_bounds__(256)
void ffnA_k(const unsigned short* __restrict__ xb,
            const unsigned short* __restrict__ W1T3, const unsigned short* __restrict__ W2T3,
            FfnP fp, unsigned short* __restrict__ h0, unsigned short* __restrict__ h1,
            float* __restrict__ out,
            const int* __restrict__ tok3, const float* __restrict__ gslot3,
            const int* __restrict__ cntk3, int ge)
{
    __shared__ __align__(16) short lds[16384];   // 32KB
    const int bx = blockIdx.x, by = blockIdx.y;
    const int col0 = bx * 128;
    if (by < 8){
        if (ge >= 24) return;
        int m = ge >> 3, e = ge & 7;
        int limit = cntk3[m*16 + e]; if (limit > CAP) limit = CAP;
        if (col0 >= limit) return;
        unsigned short* hd = (ge & 1) ? h1 : h0;
        gemm_core_t2<1, 1>(lds,
                           W1T3 + ((size_t)(m*8+e))*HDIM*DDIM, xb, fp.b1[m] + (size_t)e*HDIM,
                           hd, DDIM, HDIM, by*128, col0, limit,
                           tok3 + ((size_t)m*NEXP + e)*CAP, nullptr, nullptr);
    } else {
        int gy = ge - 1; if (gy < 0) return;
        int m = gy >> 3, e = gy & 7;
        int limit = cntk3[m*16 + e]; if (limit > CAP) limit = CAP;
        if (col0 >= limit) return;
        const unsigned short* hs = (gy & 1) ? h1 : h0;
        gemm_core_y2(lds, W2T3 + ((size_t)(m*8+e))*DDIM*HDIM, hs, fp.b2[m] + (size_t)e*DDIM,
                     out, (by-8)*64, col0, limit,
                     tok3 + ((size_t)m*NEXP + e)*CAP, gslot3 + ((size_t)m*NEXP + e)*CAP);
    }
}

// ---------- paired-domain FFN step (m1 and m2 together; disjoint token sets) ----------
// grid (128,32): by 0..7 h(m1,s); 8..15 h(m2,s); 16..23 y(m1,s-1) [or y(m0,7) at s=0]; 24..31 y(m2,s-1)
__global__ __launch_bounds__(256)
void ffnD_k(const unsigned short* __restrict__ xb,
            const unsigned short* __restrict__ W1T3, const unsigned short* __restrict__ W2T3,
            FfnP fp, unsigned short* __restrict__ h0, unsigned short* __restrict__ h1,
            unsigned short* __restrict__ h2, unsigned short* __restrict__ h3,
            float* __restrict__ out,
            const int* __restrict__ tok3, const float* __restrict__ gslot3,
            const int* __restrict__ cntk3, int s)
{
    __shared__ __align__(16) short lds[16384];   // 32KB
    const int bx = blockIdx.x, by = blockIdx.y;
    const int col0 = bx * 128;
    if (by < 16){
        if (s >= 8) return;
        int m = (by < 8) ? 1 : 2;
        int g = m*NEXP + s;
        int limit = cntk3[m*16 + s]; if (limit > CAP) limit = CAP;
        if (col0 >= limit) return;
        unsigned short* hd = (m == 1) ? ((s & 1) ? h1 : h0) : ((s & 1) ? h3 : h2);
        gemm_core_t2<1, 1>(lds,
                           W1T3 + (size_t)g*HDIM*DDIM, xb, fp.b1[m] + (size_t)s*HDIM,
                           hd, DDIM, HDIM, (by & 7)*128, col0, limit,
                           tok3 + (size_t)g*CAP, nullptr, nullptr);
    } else {
        int m, e; const unsigned short* hs_;
        if (s == 0){
            if (by >= 24) return;          // only y(m0,7) at s=0
            m = 0; e = 7; hs_ = h1;        // m0 e7 parity 1 -> h1
        } else {
            m = (by < 24) ? 1 : 2;
            e = s - 1;
            hs_ = (m == 1) ? ((e & 1) ? h1 : h0) : ((e & 1) ? h3 : h2);
        }
        int g = m*NEXP + e;
        int limit = cntk3[m*16 + e]; if (limit > CAP) limit = CAP;
        if (col0 >= limit) return;
        gemm_core_y2(lds, W2T3 + (size_t)g*DDIM*HDIM, hs_, fp.b2[m] + (size_t)e*DDIM,
                     out, ((by - 16) & 7)*64, col0, limit,
                     tok3 + (size_t)g*CAP, gslot3 + (size_t)g*CAP);
    }
}

// ---------- per-model pipelined FFN (lower tier) ----------
__global__ __launch_bounds__(256)
void ffnB_k(const unsigned short* __restrict__ xb,
            const unsigned short* __restrict__ W1T, const float* __restrict__ b1,
            const unsigned short* __restrict__ W2T, const float* __restrict__ b2,
            unsigned short* __restrict__ h0, unsigned short* __restrict__ h1,
            float* __restrict__ out,
            const int* __restrict__ tok, const float* __restrict__ gslot,
            const int* __restrict__ cntk, int eh)
{
    __shared__ __align__(16) short lds[16384];
    const int bx = blockIdx.x, by = blockIdx.y;
    const int col0 = bx * 128;
    if (by < 8){
        if (eh > 7) return;
        int limit = cntk[eh]; if (limit > CAP) limit = CAP;
        if (col0 >= limit) return;
        unsigned short* hd = (eh & 1) ? h1 : h0;
        gemm_core_t2<1, 1>(lds,
                           W1T + (size_t)eh*HDIM*DDIM, xb, b1 + (size_t)eh*HDIM,
                           hd, DDIM, HDIM, by*128, col0, limit,
                           tok + (size_t)eh*CAP, nullptr, nullptr);
    } else {
        int ey = eh - 1; if (ey < 0) return;
        int limit = cntk[ey]; if (limit > CAP) limit = CAP;
        if (col0 >= limit) return;
        const unsigned short* hs = (ey & 1) ? h1 : h0;
        gemm_core_y2(lds, W2T + (size_t)ey*DDIM*HDIM, hs, b2 + (size_t)ey*DDIM,
                     out, (by-8)*64, col0, limit,
                     tok + (size_t)ey*CAP, gslot + (size_t)ey*CAP);
    }
}

// ---------- ranking (batched over 3 models) ----------
__global__ __launch_bounds__(1024)
void rank_count3_k(const int* __restrict__ idx3, const int* __restrict__ label,
                   int* __restrict__ bcnt3)
{
    __shared__ int c[NEXP];
    const int m = blockIdx.y;
    const int* idx = idx3 + (size_t)m * NSLOT;
    int t = threadIdx.x;
    if (t < NEXP) c[t] = 0;
    __syncthreads();
    int s = blockIdx.x * 1024 + t;
    int n = s >> 1;
    int e = idx[s];
    bool valid = (m == 0) || (label[n] == m - 1);
    if (valid) atomicAdd(&c[e], 1);
    __syncthreads();
    if (t < NEXP) bcnt3[((size_t)m*128 + blockIdx.x)*NEXP + t] = c[t];
}

__global__ void rank_scan3_k(const int* __restrict__ bcnt3, int* __restrict__ boff3,
                             int* __restrict__ cntk3)
{
    int m = blockIdx.x, e = threadIdx.x;
    if (e < NEXP){
        int run = 0;
        for (int b = 0; b < NSLOT/1024; b++){
            boff3[((size_t)m*128 + b)*NEXP + e] = run;
            run += bcnt3[((size_t)m*128 + b)*NEXP + e];
        }
        cntk3[m*16 + e] = run < CAP ? run : CAP;
    }
}

__global__ __launch_bounds__(1024)
void rank_assign3_k(const int* __restrict__ idx3, const int* __restrict__ label,
                    const int* __restrict__ boff3, const float* __restrict__ gw3,
                    const float* __restrict__ dscale,
                    int* __restrict__ tok3, float* __restrict__ gs3)
{
    __shared__ int wcnt[16][NEXP];
    __shared__ int woff[16][NEXP];
    const int m = blockIdx.y;
    const int* idx = idx3 + (size_t)m * NSLOT;
    const float* gw = gw3 + (size_t)m * NSLOT;
    int t = threadIdx.x;
    int s = blockIdx.x * 1024 + t;
    int n = s >> 1;
    int e = idx[s];
    bool valid = (m == 0) || (label[n] == m - 1);
    int w = t >> 6, lane = t & 63;
    unsigned long long lt = (lane == 0) ? 0ull : ((1ull << lane) - 1ull);
    int myrank = 0;
    #pragma unroll
    for (int ei = 0; ei < NEXP; ei++){
        unsigned long long bal = __ballot(valid && (e == ei));
        if (ei == e) myrank = __popcll(bal & lt);
        if (lane == 0) wcnt[w][ei] = __popcll(bal);
    }
    __syncthreads();
    if (t < NEXP){
        int run = boff3[((size_t)m*128 + blockIdx.x)*NEXP + t];
        for (int w2 = 0; w2 < 16; w2++){
            woff[w2][t] = run;
            run += wcnt[w2][t];
        }
    }
    __syncthreads();
    int pos = woff[w][e] + myrank;
    bool keep = valid && (pos < CAP);
    if (keep){
        float scale = (m > 0) ? dscale[0] : 1.f;
        tok3[((size_t)m*NEXP + e)*CAP + pos] = n;
        gs3[((size_t)m*NEXP + e)*CAP + pos] = gw[s] * scale;
    }
}

extern "C" void kernel_launch(void* const* d_in, const int* in_sizes, int n_in,
                              void* d_out, int out_size, void* d_ws, size_t ws_size,
                              hipStream_t stream)
{
    (void)in_sizes; (void)n_in; (void)out_size;
    const float* x      = (const float*)d_in[0];
    const int*   label  = (const int*)  d_in[1];
    const float* dscale = (const float*)d_in[2];
    float* out = (float*)d_out;

    const size_t XB  = (size_t)NTOK * DDIM * 2;            // 64MB
    const size_t HS  = (size_t)CAP * HDIM * 2;             // 32MB
    const size_t WPT = (size_t)3 * PROJ * DDIM * 2;        // 768KB
    const size_t SS  = (size_t)2 * 3 * NTOK * 4;           // 1.5MB
    const size_t WN  = (size_t)3 * DDIM * 8 * 4;           // 48KB
    const size_t SMALL = WPT + SS + WN + 256 +
                         (size_t)3*PROJ*NEXP*4 +
                         (size_t)3*NSLOT*4*2 +
                         (size_t)3*NEXP*CAP*4*2 +
                         (size_t)3*128*NEXP*4*2 + 256;
    const size_t W12A = (size_t)2 * 3 * NEXP * DDIM * HDIM * 2;  // 48MB
    const size_t W12B = (size_t)2 * NEXP * DDIM * HDIM * 2;      // 16MB
    const size_t common = XB + HS + SMALL;                       // includes h0

    int tier;
    if      (ws_size >= common + 3*HS + W12A) tier = 0;   // paired-domain pipeline
    else if (ws_size >= common + HS + W12A)   tier = 1;   // cross-model pipeline
    else if (ws_size >= common + HS + W12B)   tier = 2;   // per-model pipelined
    else if (ws_size >= common + W12B)        tier = 3;   // per-model serial
    else return;  // clean failure, not a fault

    char* p = (char*)d_ws;
    unsigned short* xb   = (unsigned short*)p; p += XB;
    unsigned short* h0   = (unsigned short*)p; p += HS;
    unsigned short* WpT3 = (unsigned short*)p; p += WPT;
    float* ssbuf = (float*)p;  p += SS;
    float* Wn3   = (float*)p;  p += WN;
    float* bd3   = (float*)p;  p += 256;
    float* simn3 = (float*)p;  p += (size_t)3*PROJ*NEXP*4;
    int*   idx3  = (int*)p;    p += (size_t)3*NSLOT*4;
    float* gw3   = (float*)p;  p += (size_t)3*NSLOT*4;
    int*   tok3  = (int*)p;    p += (size_t)3*NEXP*CAP*4;
    float* gslot3= (float*)p;  p += (size_t)3*NEXP*CAP*4;
    int*   bcnt3 = (int*)p;    p += (size_t)3*128*NEXP*4;
    int*   boff3 = (int*)p;    p += (size_t)3*128*NEXP*4;
    int*   cntk3 = (int*)p;    p += 256;
    unsigned short* h1 = nullptr;
    unsigned short* h2 = nullptr;
    unsigned short* h3 = nullptr;
    if (tier <= 2){ h1 = (unsigned short*)p; p += HS; }
    if (tier == 0){ h2 = (unsigned short*)p; p += HS; h3 = (unsigned short*)p; p += HS; }
    unsigned short* Wbuf = (unsigned short*)p;

    SimArgs sa; TpArgs ta; WprodArgs wa; PssArgs pa; GfArgs gf; W12P wp; FfnP fp;
    for (int m = 0; m < 3; m++){
        ta.Wp[m] = (const float*)d_in[3 + 8*m + 0];
        wa.Wp[m] = ta.Wp[m];
        wa.bp[m] = (const float*)d_in[3 + 8*m + 1];
        pa.bp[m] = wa.bp[m];
        sa.sim[m] = (const float*)d_in[3 + 8*m + 2];
        gf.tp[m] = (const float*)d_in[3 + 8*m + 3];
        wp.W1[m] = (const float*)d_in[3 + 8*m + 4];
        fp.b1[m] = (const float*)d_in[3 + 8*m + 5];
        wp.W2[m] = (const float*)d_in[3 + 8*m + 6];
        fp.b2[m] = (const float*)d_in[3 + 8*m + 7];
    }

    // ---- prep + gate ----
    init_k<<<dim3(NTOK*DDIM/4/256), dim3(256), 0, stream>>>(
        (const float4*)x, (ushort4*)xb, (float4*)out);
    simn3_k<<<dim3(3), dim3(256), 0, stream>>>(sa, simn3);
    transWp_k<<<dim3(PROJ/32, DDIM/32, 3), dim3(32,8), 0, stream>>>(ta, WpT3);
    wprod_k<<<dim3(3), dim3(256), 0, stream>>>(wa, simn3, Wn3, bd3);
    pss_k<<<dim3(2, NTOK/128, 3), dim3(256), 0, stream>>>(WpT3, xb, pa, ssbuf);
    gatefin3_k<<<dim3(NTOK/64), dim3(256), 0, stream>>>(
        x, label, Wn3, bd3, ssbuf, gf, idx3, gw3);

    // ---- ranking ----
    rank_count3_k<<<dim3(NSLOT/1024, 3), dim3(1024), 0, stream>>>(idx3, label, bcnt3);
    rank_scan3_k<<<dim3(3), dim3(64), 0, stream>>>(bcnt3, boff3, cntk3);
    rank_assign3_k<<<dim3(NSLOT/1024, 3), dim3(1024), 0, stream>>>(
        idx3, label, boff3, gw3, dscale, tok3, gslot3);

    // ---- FFN ----
    if (tier <= 1){
        unsigned short* W1T3 = Wbuf;
        unsigned short* W2T3 = Wbuf + (size_t)3*NEXP*DDIM*HDIM;
        transW12all_k<<<dim3(32, 32, 48), dim3(32,8), 0, stream>>>(wp, W1T3, W2T3);
        if (tier == 0){
            // m0 phase: 8 balanced dispatches (h e + y e-1)
            for (int ge = 0; ge < 8; ge++)
                ffnA_k<<<dim3(128, 16), 256, 0, stream>>>(
                    xb, W1T3, W2T3, fp, h0, h1, out, tok3, gslot3, cntk3, ge);
            // paired domain phase: 9 dispatches; s=0 also carries y(m0,7)
            for (int s = 0; s <= 8; s++)
                ffnD_k<<<dim3(128, 32), 256, 0, stream>>>(
                    xb, W1T3, W2T3, fp, h0, h1, h2, h3, out, tok3, gslot3, cntk3, s);
        } else {
            for (int ge = 0; ge <= 24; ge++)
                ffnA_k<<<dim3(128, 16), 256, 0, stream>>>(
                    xb, W1T3, W2T3, fp, h0, h1, out, tok3, gslot3, cntk3, ge);
        }
    } else {
        unsigned short* W1T = Wbuf;
        unsigned short* W2T = Wbuf + (size_t)NEXP*DDIM*HDIM;
        for (int m = 0; m < 3; m++){
            trans2_k<<<dim3(32, 32, 16), dim3(32,8), 0, stream>>>(wp.W1[m], wp.W2[m], W1T, W2T);
            const int* tokm = tok3 + (size_t)m*NEXP*CAP;
            const float* gsm = gslot3 + (size_t)m*NEXP*CAP;
            const int* cntm = cntk3 + m*16;
            if (tier == 2){
                for (int eh = 0; eh <= 8; eh++)
                    ffnB_k<<<dim3(128, 16), 256, 0, stream>>>(
                        xb, W1T, fp.b1[m], W2T, fp.b2[m], h0, h1, out, tokm, gsm, cntm, eh);
            } else {
                for (int e = 0; e < NEXP; e++){
                    mgemm3_k<1, 1><<<dim3(HDIM/128, CAP/128), 256, 0, stream>>>(
                        W1T + (size_t)e*HDIM*DDIM, xb, fp.b1[m] + (size_t)e*HDIM, h0,
                        DDIM, HDIM, tokm + (size_t)e*CAP, nullptr, nullptr, cntm, e);
                    mgemm3_k<0, 3><<<dim3(DDIM/128, CAP/128), 256, 0, stream>>>(
                        W2T + (size_t)e*DDIM*HDIM, h0, fp.b2[m] + (size_t)e*DDIM, out,
                        HDIM, DDIM, nullptr, tokm + (size_t)e*CAP, gsm + (size_t)e*CAP, cntm, e);
                }
            }
        }
    }
}

// Round 15
// 1693.548 us; speedup vs baseline: 1.0340x; 1.0266x over previous
//
#include <hip/hip_runtime.h>

#define NTOK 65536
#define DDIM 512
#define HDIM 1024
#define NEXP 8
#define PROJ 256
#define CAP  16384
#define NSLOT (2*NTOK)
#define LOG100 4.605170185988091f

typedef __attribute__((ext_vector_type(8))) short bf16x8;
typedef __attribute__((ext_vector_type(4))) short short4v;
typedef __attribute__((ext_vector_type(4))) float f32x4;

// ---------- helpers ----------
__device__ inline float bf2f(unsigned short u){
    union { float f; unsigned int i; } c; c.i = ((unsigned int)u) << 16; return c.f;
}
__device__ inline unsigned short f2bf(float f){
    union { float f; unsigned int i; } c; c.f = f;
    unsigned int x = c.i;
    return (unsigned short)((x + 0x7fffu + ((x >> 16) & 1u)) >> 16); // RTNE
}
__device__ inline void gload16(const void* g, void* lds){
    __builtin_amdgcn_global_load_lds(
        (const __attribute__((address_space(1))) unsigned int*)g,
        (__attribute__((address_space(3))) unsigned int*)lds, 16, 0, 0);
}

// ---------- fused init: xb = bf16(x), out = 0 ----------
__global__ void init_k(const float4* __restrict__ x, ushort4* __restrict__ xb,
                       float4* __restrict__ out){
    long i = (long)blockIdx.x * 256 + threadIdx.x;
    float4 f = x[i];
    ushort4 u; u.x = f2bf(f.x); u.y = f2bf(f.y); u.z = f2bf(f.z); u.w = f2bf(f.w);
    xb[i] = u;
    out[i] = float4{0.f, 0.f, 0.f, 0.f};
}

// ---------- generic 32x32-tiled transpose+convert body ----------
__device__ inline void trans_body(const float* in, unsigned short* out, int R, int C){
    int rbase = blockIdx.y * 32, cbase = blockIdx.x * 32;
    if (rbase >= R || cbase >= C) return;
    __shared__ float tile[32][33];
    int tx = threadIdx.x, ty = threadIdx.y;   // (32,8)
    #pragma unroll
    for (int i = 0; i < 4; i++)
        tile[ty + i*8][tx] = in[(long)(rbase + ty + i*8) * C + cbase + tx];
    __syncthreads();
    #pragma unroll
    for (int i = 0; i < 4; i++)
        out[(long)(cbase + ty + i*8) * R + rbase + tx] = f2bf(tile[tx][ty + i*8]);
}

// per-model W1/W2 transpose (lower tiers)
__global__ __launch_bounds__(256)
void trans2_k(const float* __restrict__ W1, const float* __restrict__ W2,
              unsigned short* __restrict__ W1T, unsigned short* __restrict__ W2T)
{
    int z = blockIdx.z;
    if (z < 8) trans_body(W1 + (size_t)z*DDIM*HDIM, W1T + (size_t)z*DDIM*HDIM, DDIM, HDIM);
    else       trans_body(W2 + (size_t)(z-8)*DDIM*HDIM, W2T + (size_t)(z-8)*DDIM*HDIM, HDIM, DDIM);
}

// all-model W1/W2 transpose
struct W12P { const float* W1[3]; const float* W2[3]; };
__global__ __launch_bounds__(256)
void transW12all_k(W12P wp, unsigned short* __restrict__ W1T3, unsigned short* __restrict__ W2T3)
{
    int z = blockIdx.z, m = z >> 4, piece = z & 15;
    if (piece < 8)
        trans_body(wp.W1[m] + (size_t)piece*DDIM*HDIM,
                   W1T3 + ((size_t)m*8 + piece)*DDIM*HDIM, DDIM, HDIM);
    else
        trans_body(wp.W2[m] + (size_t)(piece-8)*DDIM*HDIM,
                   W2T3 + ((size_t)m*8 + piece-8)*DDIM*HDIM, HDIM, DDIM);
}

// Wp transpose: [512][256] f32 -> [256][512] bf16, per model
struct TpArgs { const float* Wp[3]; };
__global__ __launch_bounds__(256)
void transWp_k(TpArgs ta, unsigned short* __restrict__ WpT3)
{
    int m = blockIdx.z;
    trans_body(ta.Wp[m], WpT3 + (size_t)m*PROJ*DDIM, DDIM, PROJ);
}

// ---------- normalize sim columns ----------
struct SimArgs { const float* sim[3]; };
__global__ void simn3_k(SimArgs sa, float* __restrict__ simn3){
    __shared__ float red[256];
    const float* sim = sa.sim[blockIdx.x];
    float* simn = simn3 + (size_t)blockIdx.x * PROJ * NEXP;
    int j = threadIdx.x;
    for (int e = 0; e < NEXP; e++){
        float v = sim[j*NEXP + e];
        red[j] = v*v;
        __syncthreads();
        for (int s = 128; s > 0; s >>= 1){
            if (j < s) red[j] += red[j + s];
            __syncthreads();
        }
        float nrm = sqrtf(red[0]) + 1e-12f;
        __syncthreads();
        simn[j*NEXP + e] = v / nrm;
    }
}

// ---------- W' = Wp @ simn (fp32), bd = bp @ simn ----------
struct WprodArgs { const float* Wp[3]; const float* bp[3]; };
__global__ __launch_bounds__(256)
void wprod_k(WprodArgs wa, const float* __restrict__ simn3,
             float* __restrict__ Wn3, float* __restrict__ bd3)
{
    int m = blockIdx.x;
    __shared__ float Sn[PROJ*NEXP];
    const float* Wp = wa.Wp[m];
    int t = threadIdx.x;
    for (int i = t; i < PROJ*NEXP; i += 256) Sn[i] = simn3[(size_t)m*PROJ*NEXP + i];
    __syncthreads();
    for (int r = t; r < DDIM; r += 256){
        float d[8];
        #pragma unroll
        for (int e = 0; e < 8; e++) d[e] = 0.f;
        for (int p = 0; p < PROJ; p++){
            float w = Wp[(size_t)r*PROJ + p];
            #pragma unroll
            for (int e = 0; e < 8; e++) d[e] = fmaf(w, Sn[p*8+e], d[e]);
        }
        #pragma unroll
        for (int e = 0; e < 8; e++) Wn3[((size_t)m*DDIM + r)*8 + e] = d[e];
    }
    if (t < 8){
        float s = 0.f;
        for (int p = 0; p < PROJ; p++) s = fmaf(wa.bp[m][p], Sn[p*8+t], s);
        bd3[m*8 + t] = s;
    }
}

// ---------- pss: MFMA P-GEMM, epilogue = row-norm^2 only ----------
struct PssArgs { const float* bp[3]; };
__global__ __launch_bounds__(256)
void pss_k(const unsigned short* __restrict__ WpT3, const unsigned short* __restrict__ xb,
           PssArgs pa, float* __restrict__ ssbuf)
{
    __shared__ __align__(16) short As[128*32];
    __shared__ __align__(16) short Bs[128*32];
    __shared__ float ssl[2][128];
    const int m = blockIdx.z;
    const int row0 = blockIdx.x * 128;
    const int n0 = blockIdx.y * 128;
    const unsigned short* AT = WpT3 + (size_t)m * PROJ * DDIM;
    const float* bp = pa.bp[m];

    const int t = threadIdx.x, w = t >> 6, l = t & 63;
    const int qrow = l >> 2, kc = (l & 3) * 8;
    long arowg[2], browg[2];
    #pragma unroll
    for (int q = 0; q < 2; q++){
        arowg[q] = (long)(row0 + w*32 + q*16 + qrow) * DDIM;
        browg[q] = (long)(n0   + w*32 + q*16 + qrow) * DDIM;
    }
    const int wm = (w >> 1) * 64, wn = (w & 1) * 64;
    const int fr = l & 15, fk = l >> 4;
    const int koff = fk * 8, fk4 = fk * 4;

    f32x4 acc[4][4];
    #pragma unroll
    for (int i = 0; i < 4; i++)
        #pragma unroll
        for (int j = 0; j < 4; j++) acc[i][j] = (f32x4){0.f, 0.f, 0.f, 0.f};

    for (int k0 = 0; k0 < DDIM; k0 += 32){
        __syncthreads();
        #pragma unroll
        for (int q = 0; q < 2; q++) gload16(AT + arowg[q] + k0 + kc, As + w*1024 + q*512);
        #pragma unroll
        for (int q = 0; q < 2; q++) gload16(xb + browg[q] + k0 + kc, Bs + w*1024 + q*512);
        __syncthreads();
        bf16x8 af[4], bfv[4];
        #pragma unroll
        for (int i = 0; i < 4; i++) af[i]  = *(const bf16x8*)&As[(wm + i*16 + fr)*32 + koff];
        #pragma unroll
        for (int j = 0; j < 4; j++) bfv[j] = *(const bf16x8*)&Bs[(wn + j*16 + fr)*32 + koff];
        #pragma unroll
        for (int i = 0; i < 4; i++)
            #pragma unroll
            for (int j = 0; j < 4; j++)
                acc[i][j] = __builtin_amdgcn_mfma_f32_16x16x32_bf16(af[i], bfv[j], acc[i][j], 0, 0, 0);
    }

    float part[4];
    #pragma unroll
    for (int j = 0; j < 4; j++){
        float s = 0.f;
        #pragma unroll
        for (int i = 0; i < 4; i++){
            int mc = row0 + wm + i*16 + fk4;
            float4 bb = *(const float4*)(bp + mc);
            float v0 = acc[i][j][0] + bb.x;
            float v1 = acc[i][j][1] + bb.y;
            float v2 = acc[i][j][2] + bb.z;
            float v3 = acc[i][j][3] + bb.w;
            s += v0*v0 + v1*v1 + v2*v2 + v3*v3;
        }
        s += __shfl_xor(s, 16, 64);
        s += __shfl_xor(s, 32, 64);
        part[j] = s;
    }
    if (fk == 0){
        #pragma unroll
        for (int j = 0; j < 4; j++) ssl[w >> 1][wn + j*16 + fr] = part[j];
    }
    __syncthreads();
    if (t < 128)
        ssbuf[((size_t)blockIdx.x*3 + m)*NTOK + n0 + t] = ssl[0][t] + ssl[1][t];
}

// ---------- gatefin3: k-split GEMV, wave-uniform W s_loads ----------
struct GfArgs { const float* tp[3]; };
__global__ __launch_bounds__(256)
void gatefin3_k(const float* __restrict__ x, const int* __restrict__ label,
                const float* __restrict__ Wn3, const float* __restrict__ bd3,
                const float* __restrict__ ssbuf, GfArgs gf,
                int* __restrict__ idx3, float* __restrict__ gw3)
{
    __shared__ float pd[3][64][26];
    const int t = threadIdx.x;
    const int tok = t & 63;
    const int qu = __builtin_amdgcn_readfirstlane(t >> 6);
    const int n = blockIdx.x * 64 + tok;

    float dots[3][8];
    #pragma unroll
    for (int m = 0; m < 3; m++)
        #pragma unroll
        for (int e = 0; e < 8; e++) dots[m][e] = 0.f;

    const float4* xp = (const float4*)(x + (size_t)n * DDIM + qu * 128);
    for (int c = 0; c < 8; c++){
        float4 xv[4];
        #pragma unroll
        for (int u = 0; u < 4; u++) xv[u] = xp[c*4 + u];
        #pragma unroll
        for (int kk = 0; kk < 16; kk++){
            float a = (kk & 2) ? ((kk & 1) ? xv[kk>>2].w : xv[kk>>2].z)
                               : ((kk & 1) ? xv[kk>>2].y : xv[kk>>2].x);
            int k = qu*128 + c*16 + kk;
            #pragma unroll
            for (int m = 0; m < 3; m++){
                const float* wr = Wn3 + ((size_t)m*DDIM + k)*8;
                float4 w0 = *(const float4*)wr;
                float4 w1 = *(const float4*)(wr + 4);
                dots[m][0] = fmaf(a, w0.x, dots[m][0]);
                dots[m][1] = fmaf(a, w0.y, dots[m][1]);
                dots[m][2] = fmaf(a, w0.z, dots[m][2]);
                dots[m][3] = fmaf(a, w0.w, dots[m][3]);
                dots[m][4] = fmaf(a, w1.x, dots[m][4]);
                dots[m][5] = fmaf(a, w1.y, dots[m][5]);
                dots[m][6] = fmaf(a, w1.z, dots[m][6]);
                dots[m][7] = fmaf(a, w1.w, dots[m][7]);
            }
        }
    }
    if (qu != 0){
        #pragma unroll
        for (int m = 0; m < 3; m++)
            #pragma unroll
            for (int e = 0; e < 8; e++) pd[qu-1][tok][m*8+e] = dots[m][e];
    }
    __syncthreads();
    if (qu == 0){
        #pragma unroll
        for (int qq = 0; qq < 3; qq++)
            #pragma unroll
            for (int m = 0; m < 3; m++)
                #pragma unroll
                for (int e = 0; e < 8; e++) dots[m][e] += pd[qq][tok][m*8+e];

        int lab = label[n];
        #pragma unroll
        for (int m = 0; m < 3; m++){
            float ss = ssbuf[(0*3+m)*(size_t)NTOK + n] + ssbuf[(1*3+m)*(size_t)NTOK + n];
            float scale = expf(fminf(gf.tp[m][0], LOG100));
            float inv = scale / (sqrtf(ss) + 1e-12f);
            float l8[8], mx = -1e30f;
            #pragma unroll
            for (int e = 0; e < 8; e++){
                l8[e] = (dots[m][e] + bd3[m*8+e]) * inv;
                mx = fmaxf(mx, l8[e]);
            }
            float g[8], s = 0.f;
            #pragma unroll
            for (int e = 0; e < 8; e++){ g[e] = expf(l8[e] - mx); s += g[e]; }
            #pragma unroll
            for (int e = 0; e < 8; e++) g[e] /= s;
            int e0 = 0; float b0 = g[0];
            #pragma unroll
            for (int e = 1; e < 8; e++) if (g[e] > b0){ b0 = g[e]; e0 = e; }
            int e1 = (e0 == 0) ? 1 : 0; float b1v = g[e1];
            #pragma unroll
            for (int e = 0; e < 8; e++) if (e != e0 && g[e] > b1v){ b1v = g[e]; e1 = e; }
            float maskv = (m == 0) ? 1.f : ((lab == m - 1) ? 1.f : 0.f);
            float s2 = b0 + b1v + 1e-9f;
            size_t base = (size_t)m * NSLOT + 2*(size_t)n;
            gw3[base]   = b0 / s2 * maskv;
            gw3[base+1] = b1v / s2 * maskv;
            idx3[base]   = e0;
            idx3[base+1] = e1;
        }
    }
}

// ---------- transposed-output bf16 MFMA GEMM core, 128x128, BK=32 ----------
template<int BGATHER, int OMODE>
__device__ __forceinline__
void gemm_core_t(short* As, short* Bs,
                 const unsigned short* __restrict__ AT, const unsigned short* __restrict__ Bv,
                 const float* __restrict__ bias, void* __restrict__ Cout,
                 int Kd, int Mld, int row0, int col0, int limitN,
                 const int* __restrict__ rowidx, const int* __restrict__ otok,
                 const float* __restrict__ gs)
{
    const int t = threadIdx.x;
    const int w = t >> 6, l = t & 63;
    const int qrow = l >> 2;
    const int kc = (l & 3) * 8;

    long arowg[2], browg[2];
    #pragma unroll
    for (int q = 0; q < 2; q++){
        arowg[q] = (long)(row0 + w*32 + q*16 + qrow) * Kd;
        int s = col0 + w*32 + q*16 + qrow;
        int gi = s;
        if (BGATHER) gi = (s < limitN) ? rowidx[s] : 0;
        browg[q] = (long)gi * Kd;
    }

    const int wm = (w >> 1) * 64, wn = (w & 1) * 64;
    const int fr = l & 15, fk = l >> 4;
    const int koff = fk * 8, fk4 = fk * 4;

    f32x4 acc[4][4];
    #pragma unroll
    for (int i = 0; i < 4; i++)
        #pragma unroll
        for (int j = 0; j < 4; j++) acc[i][j] = (f32x4){0.f, 0.f, 0.f, 0.f};

    for (int k0 = 0; k0 < Kd; k0 += 32){
        __syncthreads();
        #pragma unroll
        for (int q = 0; q < 2; q++) gload16(AT + arowg[q] + k0 + kc, As + w*1024 + q*512);
        #pragma unroll
        for (int q = 0; q < 2; q++) gload16(Bv + browg[q] + k0 + kc, Bs + w*1024 + q*512);
        __syncthreads();
        bf16x8 af[4], bfv[4];
        #pragma unroll
        for (int i = 0; i < 4; i++) af[i]  = *(const bf16x8*)&As[(wm + i*16 + fr)*32 + koff];
        #pragma unroll
        for (int j = 0; j < 4; j++) bfv[j] = *(const bf16x8*)&Bs[(wn + j*16 + fr)*32 + koff];
        __builtin_amdgcn_s_setprio(1);
        #pragma unroll
        for (int i = 0; i < 4; i++)
            #pragma unroll
            for (int j = 0; j < 4; j++)
                acc[i][j] = __builtin_amdgcn_mfma_f32_16x16x32_bf16(af[i], bfv[j], acc[i][j], 0, 0, 0);
        __builtin_amdgcn_s_setprio(0);
    }

    #pragma unroll
    for (int i = 0; i < 4; i++){
        const int mc = row0 + wm + i*16 + fk4;
        float4 bb = *(const float4*)(bias + mc);
        #pragma unroll
        for (int j = 0; j < 4; j++){
            int s = col0 + wn + j*16 + fr;
            if (s < limitN){
                if (OMODE == 1){
                    ushort4 u;
                    u.x = f2bf(fmaxf(acc[i][j][0] + bb.x, 0.f));
                    u.y = f2bf(fmaxf(acc[i][j][1] + bb.y, 0.f));
                    u.z = f2bf(fmaxf(acc[i][j][2] + bb.z, 0.f));
                    u.w = f2bf(fmaxf(acc[i][j][3] + bb.w, 0.f));
                    *(ushort4*)((unsigned short*)Cout + (long)s * Mld + mc) = u;
                } else {
                    int tk = otok[s];
                    float g = gs[s];
                    float* op = (float*)Cout + (long)tk * Mld + mc;
                    float4 c = *(const float4*)op;
                    c.x += g * (acc[i][j][0] + bb.x);
                    c.y += g * (acc[i][j][1] + bb.y);
                    c.z += g * (acc[i][j][2] + bb.z);
                    c.w += g * (acc[i][j][3] + bb.w);
                    *(float4*)op = c;
                }
            }
        }
    }
}

// ---------- same core at BK=64 (two 32-k sub-buffers; fewer barrier pairs) ----------
template<int BGATHER, int OMODE>
__device__ __forceinline__
void gemm_core_t64(short* As, short* Bs,
                   const unsigned short* __restrict__ AT, const unsigned short* __restrict__ Bv,
                   const float* __restrict__ bias, void* __restrict__ Cout,
                   int Kd, int Mld, int row0, int col0, int limitN,
                   const int* __restrict__ rowidx, const int* __restrict__ otok,
                   const float* __restrict__ gs)
{
    const int t = threadIdx.x;
    const int w = t >> 6, l = t & 63;
    const int qrow = l >> 2;
    const int seg = (l & 3) * 8;

    long arowg[2], browg[2];
    #pragma unroll
    for (int q = 0; q < 2; q++){
        arowg[q] = (long)(row0 + w*32 + q*16 + qrow) * Kd;
        int s = col0 + w*32 + q*16 + qrow;
        int gi = s;
        if (BGATHER) gi = (s < limitN) ? rowidx[s] : 0;
        browg[q] = (long)gi * Kd;
    }

    const int wm = (w >> 1) * 64, wn = (w & 1) * 64;
    const int fr = l & 15, fk = l >> 4;
    const int koff = fk * 8, fk4 = fk * 4;

    f32x4 acc[4][4];
    #pragma unroll
    for (int i = 0; i < 4; i++)
        #pragma unroll
        for (int j = 0; j < 4; j++) acc[i][j] = (f32x4){0.f, 0.f, 0.f, 0.f};

    for (int k0 = 0; k0 < Kd; k0 += 64){
        __syncthreads();
        #pragma unroll
        for (int ks = 0; ks < 2; ks++)
            #pragma unroll
            for (int q = 0; q < 2; q++)
                gload16(AT + arowg[q] + k0 + ks*32 + seg, As + ks*4096 + w*1024 + q*512);
        #pragma unroll
        for (int ks = 0; ks < 2; ks++)
            #pragma unroll
            for (int q = 0; q < 2; q++)
                gload16(Bv + browg[q] + k0 + ks*32 + seg, Bs + ks*4096 + w*1024 + q*512);
        __syncthreads();
        #pragma unroll
        for (int ks = 0; ks < 2; ks++){
            bf16x8 af[4], bfv[4];
            #pragma unroll
            for (int i = 0; i < 4; i++) af[i]  = *(const bf16x8*)&As[ks*4096 + (wm + i*16 + fr)*32 + koff];
            #pragma unroll
            for (int j = 0; j < 4; j++) bfv[j] = *(const bf16x8*)&Bs[ks*4096 + (wn + j*16 + fr)*32 + koff];
            __builtin_amdgcn_s_setprio(1);
            #pragma unroll
            for (int i = 0; i < 4; i++)
                #pragma unroll
                for (int j = 0; j < 4; j++)
                    acc[i][j] = __builtin_amdgcn_mfma_f32_16x16x32_bf16(af[i], bfv[j], acc[i][j], 0, 0, 0);
            __builtin_amdgcn_s_setprio(0);
        }
    }

    #pragma unroll
    for (int i = 0; i < 4; i++){
        const int mc = row0 + wm + i*16 + fk4;
        float4 bb = *(const float4*)(bias + mc);
        #pragma unroll
        for (int j = 0; j < 4; j++){
            int s = col0 + wn + j*16 + fr;
            if (s < limitN){
                if (OMODE == 1){
                    ushort4 u;
                    u.x = f2bf(fmaxf(acc[i][j][0] + bb.x, 0.f));
                    u.y = f2bf(fmaxf(acc[i][j][1] + bb.y, 0.f));
                    u.z = f2bf(fmaxf(acc[i][j][2] + bb.z, 0.f));
                    u.w = f2bf(fmaxf(acc[i][j][3] + bb.w, 0.f));
                    *(ushort4*)((unsigned short*)Cout + (long)s * Mld + mc) = u;
                } else {
                    int tk = otok[s];
                    float g = gs[s];
                    float* op = (float*)Cout + (long)tk * Mld + mc;
                    float4 c = *(const float4*)op;
                    c.x += g * (acc[i][j][0] + bb.x);
                    c.y += g * (acc[i][j][1] + bb.y);
                    c.z += g * (acc[i][j][2] + bb.z);
                    c.w += g * (acc[i][j][3] + bb.w);
                    *(float4*)op = c;
                }
            }
        }
    }
}

// ---------- y-GEMM core: 64 feat x 128 slots, BK=64 ----------
__device__ __forceinline__
void gemm_core_y64(short* lds,
                   const unsigned short* __restrict__ AT, const unsigned short* __restrict__ Bv,
                   const float* __restrict__ bias, float* __restrict__ out,
                   int row0, int col0, int limitN,
                   const int* __restrict__ otok, const float* __restrict__ gs)
{
    short* As = lds;
    short* Bs = lds + 4096;
    const int t = threadIdx.x, w = t >> 6, l = t & 63;
    const int seg = (l & 3) * 8;

    const long arow = (long)(row0 + w*16 + (l >> 2)) * HDIM;
    long brow[2];
    #pragma unroll
    for (int hh = 0; hh < 2; hh++)
        brow[hh] = (long)(col0 + w*32 + hh*16 + (l >> 2)) * HDIM;

    const int wm = (w >> 1) * 32, wn = (w & 1) * 64;
    const int fr = l & 15, fk = l >> 4;
    const int koff = fk * 8, fk4 = fk * 4;

    f32x4 acc[2][4];
    #pragma unroll
    for (int i = 0; i < 2; i++)
        #pragma unroll
        for (int j = 0; j < 4; j++) acc[i][j] = (f32x4){0.f, 0.f, 0.f, 0.f};

    for (int k0 = 0; k0 < HDIM; k0 += 64){
        __syncthreads();
        #pragma unroll
        for (int ks = 0; ks < 2; ks++)
            gload16(AT + arow + k0 + ks*32 + seg, As + ks*2048 + w*512);
        #pragma unroll
        for (int ks = 0; ks < 2; ks++)
            #pragma unroll
            for (int hh = 0; hh < 2; hh++)
                gload16(Bv + brow[hh] + k0 + ks*32 + seg, Bs + ks*4096 + w*1024 + hh*512);
        __syncthreads();
        #pragma unroll
        for (int ks = 0; ks < 2; ks++){
            bf16x8 af[2], bfv[4];
            #pragma unroll
            for (int i = 0; i < 2; i++)
                af[i] = *(const bf16x8*)&As[ks*2048 + (wm + i*16 + fr)*32 + koff];
            #pragma unroll
            for (int j = 0; j < 4; j++)
                bfv[j] = *(const bf16x8*)&Bs[ks*4096 + (wn + j*16 + fr)*32 + koff];
            __builtin_amdgcn_s_setprio(1);
            #pragma unroll
            for (int i = 0; i < 2; i++)
                #pragma unroll
                for (int j = 0; j < 4; j++)
                    acc[i][j] = __builtin_amdgcn_mfma_f32_16x16x32_bf16(af[i], bfv[j], acc[i][j], 0, 0, 0);
            __builtin_amdgcn_s_setprio(0);
        }
    }

    #pragma unroll
    for (int i = 0; i < 2; i++){
        const int mc = row0 + wm + i*16 + fk4;
        float4 bb = *(const float4*)(bias + mc);
        #pragma unroll
        for (int j = 0; j < 4; j++){
            int s = col0 + wn + j*16 + fr;
            if (s < limitN){
                int tk = otok[s];
                float g = gs[s];
                float* op = out + (long)tk * DDIM + mc;
                float4 c = *(const float4*)op;
                c.x += g * (acc[i][j][0] + bb.x);
                c.y += g * (acc[i][j][1] + bb.y);
                c.z += g * (acc[i][j][2] + bb.z);
                c.w += g * (acc[i][j][3] + bb.w);
                *(float4*)op = c;
            }
        }
    }
}

// ---------- serial GEMM (lowest tier) ----------
template<int BGATHER, int OMODE>
__global__ __launch_bounds__(256)
void mgemm3_k(const unsigned short* __restrict__ AT, const unsigned short* __restrict__ Bv,
              const float* __restrict__ bias, void* __restrict__ Cout,
              int Kd, int Mld,
              const int* __restrict__ rowidx, const int* __restrict__ otok,
              const float* __restrict__ gs, const int* __restrict__ cntp, int cnti)
{
    __shared__ __align__(16) short As[128*32];
    __shared__ __align__(16) short Bs[128*32];
    int limit = cntp[cnti]; if (limit > CAP) limit = CAP;
    int row0 = blockIdx.x * 128, col0 = blockIdx.y * 128;
    if (col0 >= limit) return;
    gemm_core_t<BGATHER, OMODE>(As, Bs, AT, Bv, bias, Cout, Kd, Mld,
                                row0, col0, limit, rowidx, otok, gs);
}

// ---------- cross-model pipelined FFN (round-11 balanced config) ----------
// grid (128,16): by 0..7 h(ge) t64 128-feat blocks; by 8..15 y64(ge-1) 64-feat slices
struct FfnP { const float* b1[3]; const float* b2[3]; };
__global__ __launch_bounds__(256)
void ffnA_k(const unsigned short* __restrict__ xb,
            const unsigned short* __restrict__ W1T3, const unsigned short* __restrict__ W2T3,
            FfnP fp, unsigned short* __restrict__ h0, unsigned short* __restrict__ h1,
            float* __restrict__ out,
            const int* __restrict__ tok3, const float* __restrict__ gslot3,
            const int* __restrict__ cntk3, int ge)
{
    __shared__ __align__(16) short lds[16384];   // 32KB
    const int bx = blockIdx.x, by = blockIdx.y;
    const int col0 = bx * 128;
    if (by < 8){
        if (ge >= 24) return;
        int m = ge >> 3, e = ge & 7;
        int limit = cntk3[m*16 + e]; if (limit > CAP) limit = CAP;
        if (col0 >= limit) return;
        unsigned short* hd = (ge & 1) ? h1 : h0;
        gemm_core_t64<1, 1>(lds, lds + 8192,
                            W1T3 + ((size_t)(m*8+e))*HDIM*DDIM, xb, fp.b1[m] + (size_t)e*HDIM,
                            hd, DDIM, HDIM, by*128, col0, limit,
                            tok3 + ((size_t)m*NEXP + e)*CAP, nullptr, nullptr);
    } else {
        int gy = ge - 1; if (gy < 0) return;
        int m = gy >> 3, e = gy & 7;
        int limit = cntk3[m*16 + e]; if (limit > CAP) limit = CAP;
        if (col0 >= limit) return;
        const unsigned short* hs = (gy & 1) ? h1 : h0;
        gemm_core_y64(lds, W2T3 + ((size_t)(m*8+e))*DDIM*HDIM, hs, fp.b2[m] + (size_t)e*DDIM,
                      out, (by-8)*64, col0, limit,
                      tok3 + ((size_t)m*NEXP + e)*CAP, gslot3 + ((size_t)m*NEXP + e)*CAP);
    }
}

// ---------- paired-domain FFN step (m1 and m2 together; disjoint token sets) ----------
// grid (128,32): by 0..7 h(m1,s); 8..15 h(m2,s); 16..23 y(m1,s-1) [or y(m0,7) at s=0]; 24..31 y(m2,s-1)
__global__ __launch_bounds__(256)
void ffnD_k(const unsigned short* __restrict__ xb,
            const unsigned short* __restrict__ W1T3, const unsigned short* __restrict__ W2T3,
            FfnP fp, unsigned short* __restrict__ h0, unsigned short* __restrict__ h1,
            unsigned short* __restrict__ h2, unsigned short* __restrict__ h3,
            float* __restrict__ out,
            const int* __restrict__ tok3, const float* __restrict__ gslot3,
            const int* __restrict__ cntk3, int s)
{
    __shared__ __align__(16) short lds[16384];
    const int bx = blockIdx.x, by = blockIdx.y;
    const int col0 = bx * 128;
    if (by < 16){
        if (s >= 8) return;
        int m = (by < 8) ? 1 : 2;
        int g = m*NEXP + s;
        int limit = cntk3[m*16 + s]; if (limit > CAP) limit = CAP;
        if (col0 >= limit) return;
        unsigned short* hd = (m == 1) ? ((s & 1) ? h1 : h0) : ((s & 1) ? h3 : h2);
        gemm_core_t64<1, 1>(lds, lds + 8192,
                            W1T3 + (size_t)g*HDIM*DDIM, xb, fp.b1[m] + (size_t)s*HDIM,
                            hd, DDIM, HDIM, (by & 7)*128, col0, limit,
                            tok3 + (size_t)g*CAP, nullptr, nullptr);
    } else {
        int m, e; const unsigned short* hs_;
        if (s == 0){
            if (by >= 24) return;          // only y(m0,7) at s=0
            m = 0; e = 7; hs_ = h1;        // m0 e7 parity 1 -> h1
        } else {
            m = (by < 24) ? 1 : 2;
            e = s - 1;
            hs_ = (m == 1) ? ((e & 1) ? h1 : h0) : ((e & 1) ? h3 : h2);
        }
        int g = m*NEXP + e;
        int limit = cntk3[m*16 + e]; if (limit > CAP) limit = CAP;
        if (col0 >= limit) return;
        gemm_core_y64(lds, W2T3 + (size_t)g*DDIM*HDIM, hs_, fp.b2[m] + (size_t)e*DDIM,
                      out, ((by - 16) & 7)*64, col0, limit,
                      tok3 + (size_t)g*CAP, gslot3 + (size_t)g*CAP);
    }
}

// ---------- per-model pipelined FFN (lower tier) ----------
__global__ __launch_bounds__(256)
void ffnB_k(const unsigned short* __restrict__ xb,
            const unsigned short* __restrict__ W1T, const float* __restrict__ b1,
            const unsigned short* __restrict__ W2T, const float* __restrict__ b2,
            unsigned short* __restrict__ h0, unsigned short* __restrict__ h1,
            float* __restrict__ out,
            const int* __restrict__ tok, const float* __restrict__ gslot,
            const int* __restrict__ cntk, int eh)
{
    __shared__ __align__(16) short lds[16384];
    const int bx = blockIdx.x, by = blockIdx.y;
    const int col0 = bx * 128;
    if (by < 8){
        if (eh > 7) return;
        int limit = cntk[eh]; if (limit > CAP) limit = CAP;
        if (col0 >= limit) return;
        unsigned short* hd = (eh & 1) ? h1 : h0;
        gemm_core_t64<1, 1>(lds, lds + 8192,
                            W1T + (size_t)eh*HDIM*DDIM, xb, b1 + (size_t)eh*HDIM,
                            hd, DDIM, HDIM, by*128, col0, limit,
                            tok + (size_t)eh*CAP, nullptr, nullptr);
    } else {
        int ey = eh - 1; if (ey < 0) return;
        int limit = cntk[ey]; if (limit > CAP) limit = CAP;
        if (col0 >= limit) return;
        const unsigned short* hs = (ey & 1) ? h1 : h0;
        gemm_core_y64(lds, W2T + (size_t)ey*DDIM*HDIM, hs, b2 + (size_t)ey*DDIM,
                      out, (by-8)*64, col0, limit,
                      tok + (size_t)ey*CAP, gslot + (size_t)ey*CAP);
    }
}

// ---------- ranking (batched over 3 models) ----------
__global__ __launch_bounds__(1024)
void rank_count3_k(const int* __restrict__ idx3, const int* __restrict__ label,
                   int* __restrict__ bcnt3)
{
    __shared__ int c[NEXP];
    const int m = blockIdx.y;
    const int* idx = idx3 + (size_t)m * NSLOT;
    int t = threadIdx.x;
    if (t < NEXP) c[t] = 0;
    __syncthreads();
    int s = blockIdx.x * 1024 + t;
    int n = s >> 1;
    int e = idx[s];
    bool valid = (m == 0) || (label[n] == m - 1);
    if (valid) atomicAdd(&c[e], 1);
    __syncthreads();
    if (t < NEXP) bcnt3[((size_t)m*128 + blockIdx.x)*NEXP + t] = c[t];
}

__global__ void rank_scan3_k(const int* __restrict__ bcnt3, int* __restrict__ boff3,
                             int* __restrict__ cntk3)
{
    int m = blockIdx.x, e = threadIdx.x;
    if (e < NEXP){
        int run = 0;
        for (int b = 0; b < NSLOT/1024; b++){
            boff3[((size_t)m*128 + b)*NEXP + e] = run;
            run += bcnt3[((size_t)m*128 + b)*NEXP + e];
        }
        cntk3[m*16 + e] = run < CAP ? run : CAP;
    }
}

__global__ __launch_bounds__(1024)
void rank_assign3_k(const int* __restrict__ idx3, const int* __restrict__ label,
                    const int* __restrict__ boff3, const float* __restrict__ gw3,
                    const float* __restrict__ dscale,
                    int* __restrict__ tok3, float* __restrict__ gs3)
{
    __shared__ int wcnt[16][NEXP];
    __shared__ int woff[16][NEXP];
    const int m = blockIdx.y;
    const int* idx = idx3 + (size_t)m * NSLOT;
    const float* gw = gw3 + (size_t)m * NSLOT;
    int t = threadIdx.x;
    int s = blockIdx.x * 1024 + t;
    int n = s >> 1;
    int e = idx[s];
    bool valid = (m == 0) || (label[n] == m - 1);
    int w = t >> 6, lane = t & 63;
    unsigned long long lt = (lane == 0) ? 0ull : ((1ull << lane) - 1ull);
    int myrank = 0;
    #pragma unroll
    for (int ei = 0; ei < NEXP; ei++){
        unsigned long long bal = __ballot(valid && (e == ei));
        if (ei == e) myrank = __popcll(bal & lt);
        if (lane == 0) wcnt[w][ei] = __popcll(bal);
    }
    __syncthreads();
    if (t < NEXP){
        int run = boff3[((size_t)m*128 + blockIdx.x)*NEXP + t];
        for (int w2 = 0; w2 < 16; w2++){
            woff[w2][t] = run;
            run += wcnt[w2][t];
        }
    }
    __syncthreads();
    int pos = woff[w][e] + myrank;
    bool keep = valid && (pos < CAP);
    if (keep){
        float scale = (m > 0) ? dscale[0] : 1.f;
        tok3[((size_t)m*NEXP + e)*CAP + pos] = n;
        gs3[((size_t)m*NEXP + e)*CAP + pos] = gw[s] * scale;
    }
}

extern "C" void kernel_launch(void* const* d_in, const int* in_sizes, int n_in,
                              void* d_out, int out_size, void* d_ws, size_t ws_size,
                              hipStream_t stream)
{
    (void)in_sizes; (void)n_in; (void)out_size;
    const float* x      = (const float*)d_in[0];
    const int*   label  = (const int*)  d_in[1];
    const float* dscale = (const float*)d_in[2];
    float* out = (float*)d_out;

    const size_t XB  = (size_t)NTOK * DDIM * 2;            // 64MB
    const size_t HS  = (size_t)CAP * HDIM * 2;             // 32MB
    const size_t WPT = (size_t)3 * PROJ * DDIM * 2;        // 768KB
    const size_t SS  = (size_t)2 * 3 * NTOK * 4;           // 1.5MB
    const size_t WN  = (size_t)3 * DDIM * 8 * 4;           // 48KB
    const size_t SMALL = WPT + SS + WN + 256 +
                         (size_t)3*PROJ*NEXP*4 +
                         (size_t)3*NSLOT*4*2 +
                         (size_t)3*NEXP*CAP*4*2 +
                         (size_t)3*128*NEXP*4*2 + 256;
    const size_t W12A = (size_t)2 * 3 * NEXP * DDIM * HDIM * 2;  // 48MB
    const size_t W12B = (size_t)2 * NEXP * DDIM * HDIM * 2;      // 16MB
    const size_t common = XB + HS + SMALL;                       // includes h0

    int tier;
    if      (ws_size >= common + 3*HS + W12A) tier = 0;   // paired-domain pipeline
    else if (ws_size >= common + HS + W12A)   tier = 1;   // cross-model pipeline
    else if (ws_size >= common + HS + W12B)   tier = 2;   // per-model pipelined
    else if (ws_size >= common + W12B)        tier = 3;   // per-model serial
    else return;  // clean failure, not a fault

    char* p = (char*)d_ws;
    unsigned short* xb   = (unsigned short*)p; p += XB;
    unsigned short* h0   = (unsigned short*)p; p += HS;
    unsigned short* WpT3 = (unsigned short*)p; p += WPT;
    float* ssbuf = (float*)p;  p += SS;
    float* Wn3   = (float*)p;  p += WN;
    float* bd3   = (float*)p;  p += 256;
    float* simn3 = (float*)p;  p += (size_t)3*PROJ*NEXP*4;
    int*   idx3  = (int*)p;    p += (size_t)3*NSLOT*4;
    float* gw3   = (float*)p;  p += (size_t)3*NSLOT*4;
    int*   tok3  = (int*)p;    p += (size_t)3*NEXP*CAP*4;
    float* gslot3= (float*)p;  p += (size_t)3*NEXP*CAP*4;
    int*   bcnt3 = (int*)p;    p += (size_t)3*128*NEXP*4;
    int*   boff3 = (int*)p;    p += (size_t)3*128*NEXP*4;
    int*   cntk3 = (int*)p;    p += 256;
    unsigned short* h1 = nullptr;
    unsigned short* h2 = nullptr;
    unsigned short* h3 = nullptr;
    if (tier <= 2){ h1 = (unsigned short*)p; p += HS; }
    if (tier == 0){ h2 = (unsigned short*)p; p += HS; h3 = (unsigned short*)p; p += HS; }
    unsigned short* Wbuf = (unsigned short*)p;

    SimArgs sa; TpArgs ta; WprodArgs wa; PssArgs pa; GfArgs gf; W12P wp; FfnP fp;
    for (int m = 0; m < 3; m++){
        ta.Wp[m] = (const float*)d_in[3 + 8*m + 0];
        wa.Wp[m] = ta.Wp[m];
        wa.bp[m] = (const float*)d_in[3 + 8*m + 1];
        pa.bp[m] = wa.bp[m];
        sa.sim[m] = (const float*)d_in[3 + 8*m + 2];
        gf.tp[m] = (const float*)d_in[3 + 8*m + 3];
        wp.W1[m] = (const float*)d_in[3 + 8*m + 4];
        fp.b1[m] = (const float*)d_in[3 + 8*m + 5];
        wp.W2[m] = (const float*)d_in[3 + 8*m + 6];
        fp.b2[m] = (const float*)d_in[3 + 8*m + 7];
    }

    // ---- prep + gate ----
    init_k<<<dim3(NTOK*DDIM/4/256), dim3(256), 0, stream>>>(
        (const float4*)x, (ushort4*)xb, (float4*)out);
    simn3_k<<<dim3(3), dim3(256), 0, stream>>>(sa, simn3);
    transWp_k<<<dim3(PROJ/32, DDIM/32, 3), dim3(32,8), 0, stream>>>(ta, WpT3);
    wprod_k<<<dim3(3), dim3(256), 0, stream>>>(wa, simn3, Wn3, bd3);
    pss_k<<<dim3(2, NTOK/128, 3), dim3(256), 0, stream>>>(WpT3, xb, pa, ssbuf);
    gatefin3_k<<<dim3(NTOK/64), dim3(256), 0, stream>>>(
        x, label, Wn3, bd3, ssbuf, gf, idx3, gw3);

    // ---- ranking ----
    rank_count3_k<<<dim3(NSLOT/1024, 3), dim3(1024), 0, stream>>>(idx3, label, bcnt3);
    rank_scan3_k<<<dim3(3), dim3(64), 0, stream>>>(bcnt3, boff3, cntk3);
    rank_assign3_k<<<dim3(NSLOT/1024, 3), dim3(1024), 0, stream>>>(
        idx3, label, boff3, gw3, dscale, tok3, gslot3);

    // ---- FFN ----
    if (tier <= 1){
        unsigned short* W1T3 = Wbuf;
        unsigned short* W2T3 = Wbuf + (size_t)3*NEXP*DDIM*HDIM;
        transW12all_k<<<dim3(32, 32, 48), dim3(32,8), 0, stream>>>(wp, W1T3, W2T3);
        if (tier == 0){
            // m0 phase: 8 balanced dispatches (h e + y e-1)
            for (int ge = 0; ge < 8; ge++)
                ffnA_k<<<dim3(128, 16), 256, 0, stream>>>(
                    xb, W1T3, W2T3, fp, h0, h1, out, tok3, gslot3, cntk3, ge);
            // paired domain phase: 9 dispatches; s=0 also carries y(m0,7)
            for (int s = 0; s <= 8; s++)
                ffnD_k<<<dim3(128, 32), 256, 0, stream>>>(
                    xb, W1T3, W2T3, fp, h0, h1, h2, h3, out, tok3, gslot3, cntk3, s);
        } else {
            for (int ge = 0; ge <= 24; ge++)
                ffnA_k<<<dim3(128, 16), 256, 0, stream>>>(
                    xb, W1T3, W2T3, fp, h0, h1, out, tok3, gslot3, cntk3, ge);
        }
    } else {
        unsigned short* W1T = Wbuf;
        unsigned short* W2T = Wbuf + (size_t)NEXP*DDIM*HDIM;
        for (int m = 0; m < 3; m++){
            trans2_k<<<dim3(32, 32, 16), dim3(32,8), 0, stream>>>(wp.W1[m], wp.W2[m], W1T, W2T);
            const int* tokm = tok3 + (size_t)m*NEXP*CAP;
            const float* gsm = gslot3 + (size_t)m*NEXP*CAP;
            const int* cntm = cntk3 + m*16;
            if (tier == 2){
                for (int eh = 0; eh <= 8; eh++)
                    ffnB_k<<<dim3(128, 16), 256, 0, stream>>>(
                        xb, W1T, fp.b1[m], W2T, fp.b2[m], h0, h1, out, tokm, gsm, cntm, eh);
            } else {
                for (int e = 0; e < NEXP; e++){
                    mgemm3_k<1, 1><<<dim3(HDIM/128, CAP/128), 256, 0, stream>>>(
                        W1T + (size_t)e*HDIM*DDIM, xb, fp.b1[m] + (size_t)e*HDIM, h0,
                        DDIM, HDIM, tokm + (size_t)e*CAP, nullptr, nullptr, cntm, e);
                    mgemm3_k<0, 3><<<dim3(DDIM/128, CAP/128), 256, 0, stream>>>(
                        W2T + (size_t)e*DDIM*HDIM, h0, fp.b2[m] + (size_t)e*DDIM, out,
                        HDIM, DDIM, nullptr, tokm + (size_t)e*CAP, gsm + (size_t)e*CAP, cntm, e);
                }
            }
        }
    }
}

// Round 16
// 1642.979 us; speedup vs baseline: 1.0658x; 1.0308x over previous
//
#include <hip/hip_runtime.h>

#define NTOK 65536
#define DDIM 512
#define HDIM 1024
#define NEXP 8
#define PROJ 256
#define CAP  16384
#define NSLOT (2*NTOK)
#define LOG100 4.605170185988091f

typedef __attribute__((ext_vector_type(8))) short bf16x8;
typedef __attribute__((ext_vector_type(4))) short short4v;
typedef __attribute__((ext_vector_type(4))) float f32x4;

// ---------- helpers ----------
__device__ inline float bf2f(unsigned short u){
    union { float f; unsigned int i; } c; c.i = ((unsigned int)u) << 16; return c.f;
}
__device__ inline unsigned short f2bf(float f){
    union { float f; unsigned int i; } c; c.f = f;
    unsigned int x = c.i;
    return (unsigned short)((x + 0x7fffu + ((x >> 16) & 1u)) >> 16); // RTNE
}
__device__ inline void gload16(const void* g, void* lds){
    __builtin_amdgcn_global_load_lds(
        (const __attribute__((address_space(1))) unsigned int*)g,
        (__attribute__((address_space(3))) unsigned int*)lds, 16, 0, 0);
}

// ---------- fused init: xb = bf16(x), out = 0 ----------
__global__ void init_k(const float4* __restrict__ x, ushort4* __restrict__ xb,
                       float4* __restrict__ out){
    long i = (long)blockIdx.x * 256 + threadIdx.x;
    float4 f = x[i];
    ushort4 u; u.x = f2bf(f.x); u.y = f2bf(f.y); u.z = f2bf(f.z); u.w = f2bf(f.w);
    xb[i] = u;
    out[i] = float4{0.f, 0.f, 0.f, 0.f};
}

// ---------- generic 32x32-tiled transpose+convert body ----------
__device__ inline void trans_body(const float* in, unsigned short* out, int R, int C){
    int rbase = blockIdx.y * 32, cbase = blockIdx.x * 32;
    if (rbase >= R || cbase >= C) return;
    __shared__ float tile[32][33];
    int tx = threadIdx.x, ty = threadIdx.y;   // (32,8)
    #pragma unroll
    for (int i = 0; i < 4; i++)
        tile[ty + i*8][tx] = in[(long)(rbase + ty + i*8) * C + cbase + tx];
    __syncthreads();
    #pragma unroll
    for (int i = 0; i < 4; i++)
        out[(long)(cbase + ty + i*8) * R + rbase + tx] = f2bf(tile[tx][ty + i*8]);
}

// per-model W1/W2 transpose (lower tiers)
__global__ __launch_bounds__(256)
void trans2_k(const float* __restrict__ W1, const float* __restrict__ W2,
              unsigned short* __restrict__ W1T, unsigned short* __restrict__ W2T)
{
    int z = blockIdx.z;
    if (z < 8) trans_body(W1 + (size_t)z*DDIM*HDIM, W1T + (size_t)z*DDIM*HDIM, DDIM, HDIM);
    else       trans_body(W2 + (size_t)(z-8)*DDIM*HDIM, W2T + (size_t)(z-8)*DDIM*HDIM, HDIM, DDIM);
}

// all-model W1/W2 transpose
struct W12P { const float* W1[3]; const float* W2[3]; };
__global__ __launch_bounds__(256)
void transW12all_k(W12P wp, unsigned short* __restrict__ W1T3, unsigned short* __restrict__ W2T3)
{
    int z = blockIdx.z, m = z >> 4, piece = z & 15;
    if (piece < 8)
        trans_body(wp.W1[m] + (size_t)piece*DDIM*HDIM,
                   W1T3 + ((size_t)m*8 + piece)*DDIM*HDIM, DDIM, HDIM);
    else
        trans_body(wp.W2[m] + (size_t)(piece-8)*DDIM*HDIM,
                   W2T3 + ((size_t)m*8 + piece-8)*DDIM*HDIM, HDIM, DDIM);
}

// Wp transpose: [512][256] f32 -> [256][512] bf16, per model
struct TpArgs { const float* Wp[3]; };
__global__ __launch_bounds__(256)
void transWp_k(TpArgs ta, unsigned short* __restrict__ WpT3)
{
    int m = blockIdx.z;
    trans_body(ta.Wp[m], WpT3 + (size_t)m*PROJ*DDIM, DDIM, PROJ);
}

// ---------- normalize sim columns ----------
struct SimArgs { const float* sim[3]; };
__global__ void simn3_k(SimArgs sa, float* __restrict__ simn3){
    __shared__ float red[256];
    const float* sim = sa.sim[blockIdx.x];
    float* simn = simn3 + (size_t)blockIdx.x * PROJ * NEXP;
    int j = threadIdx.x;
    for (int e = 0; e < NEXP; e++){
        float v = sim[j*NEXP + e];
        red[j] = v*v;
        __syncthreads();
        for (int s = 128; s > 0; s >>= 1){
            if (j < s) red[j] += red[j + s];
            __syncthreads();
        }
        float nrm = sqrtf(red[0]) + 1e-12f;
        __syncthreads();
        simn[j*NEXP + e] = v / nrm;
    }
}

// ---------- W' = Wp @ simn (fp32), bd = bp @ simn ----------
struct WprodArgs { const float* Wp[3]; const float* bp[3]; };
__global__ __launch_bounds__(256)
void wprod_k(WprodArgs wa, const float* __restrict__ simn3,
             float* __restrict__ Wn3, float* __restrict__ bd3)
{
    int m = blockIdx.x;
    __shared__ float Sn[PROJ*NEXP];
    const float* Wp = wa.Wp[m];
    int t = threadIdx.x;
    for (int i = t; i < PROJ*NEXP; i += 256) Sn[i] = simn3[(size_t)m*PROJ*NEXP + i];
    __syncthreads();
    for (int r = t; r < DDIM; r += 256){
        float d[8];
        #pragma unroll
        for (int e = 0; e < 8; e++) d[e] = 0.f;
        for (int p = 0; p < PROJ; p++){
            float w = Wp[(size_t)r*PROJ + p];
            #pragma unroll
            for (int e = 0; e < 8; e++) d[e] = fmaf(w, Sn[p*8+e], d[e]);
        }
        #pragma unroll
        for (int e = 0; e < 8; e++) Wn3[((size_t)m*DDIM + r)*8 + e] = d[e];
    }
    if (t < 8){
        float s = 0.f;
        for (int p = 0; p < PROJ; p++) s = fmaf(wa.bp[m][p], Sn[p*8+t], s);
        bd3[m*8 + t] = s;
    }
}

// ---------- pss: MFMA P-GEMM, epilogue = row-norm^2 only ----------
struct PssArgs { const float* bp[3]; };
__global__ __launch_bounds__(256)
void pss_k(const unsigned short* __restrict__ WpT3, const unsigned short* __restrict__ xb,
           PssArgs pa, float* __restrict__ ssbuf)
{
    __shared__ __align__(16) short As[128*32];
    __shared__ __align__(16) short Bs[128*32];
    __shared__ float ssl[2][128];
    const int m = blockIdx.z;
    const int row0 = blockIdx.x * 128;
    const int n0 = blockIdx.y * 128;
    const unsigned short* AT = WpT3 + (size_t)m * PROJ * DDIM;
    const float* bp = pa.bp[m];

    const int t = threadIdx.x, w = t >> 6, l = t & 63;
    const int qrow = l >> 2, kc = (l & 3) * 8;
    long arowg[2], browg[2];
    #pragma unroll
    for (int q = 0; q < 2; q++){
        arowg[q] = (long)(row0 + w*32 + q*16 + qrow) * DDIM;
        browg[q] = (long)(n0   + w*32 + q*16 + qrow) * DDIM;
    }
    const int wm = (w >> 1) * 64, wn = (w & 1) * 64;
    const int fr = l & 15, fk = l >> 4;
    const int koff = fk * 8, fk4 = fk * 4;

    f32x4 acc[4][4];
    #pragma unroll
    for (int i = 0; i < 4; i++)
        #pragma unroll
        for (int j = 0; j < 4; j++) acc[i][j] = (f32x4){0.f, 0.f, 0.f, 0.f};

    for (int k0 = 0; k0 < DDIM; k0 += 32){
        __syncthreads();
        #pragma unroll
        for (int q = 0; q < 2; q++) gload16(AT + arowg[q] + k0 + kc, As + w*1024 + q*512);
        #pragma unroll
        for (int q = 0; q < 2; q++) gload16(xb + browg[q] + k0 + kc, Bs + w*1024 + q*512);
        __syncthreads();
        bf16x8 af[4], bfv[4];
        #pragma unroll
        for (int i = 0; i < 4; i++) af[i]  = *(const bf16x8*)&As[(wm + i*16 + fr)*32 + koff];
        #pragma unroll
        for (int j = 0; j < 4; j++) bfv[j] = *(const bf16x8*)&Bs[(wn + j*16 + fr)*32 + koff];
        #pragma unroll
        for (int i = 0; i < 4; i++)
            #pragma unroll
            for (int j = 0; j < 4; j++)
                acc[i][j] = __builtin_amdgcn_mfma_f32_16x16x32_bf16(af[i], bfv[j], acc[i][j], 0, 0, 0);
    }

    float part[4];
    #pragma unroll
    for (int j = 0; j < 4; j++){
        float s = 0.f;
        #pragma unroll
        for (int i = 0; i < 4; i++){
            int mc = row0 + wm + i*16 + fk4;
            float4 bb = *(const float4*)(bp + mc);
            float v0 = acc[i][j][0] + bb.x;
            float v1 = acc[i][j][1] + bb.y;
            float v2 = acc[i][j][2] + bb.z;
            float v3 = acc[i][j][3] + bb.w;
            s += v0*v0 + v1*v1 + v2*v2 + v3*v3;
        }
        s += __shfl_xor(s, 16, 64);
        s += __shfl_xor(s, 32, 64);
        part[j] = s;
    }
    if (fk == 0){
        #pragma unroll
        for (int j = 0; j < 4; j++) ssl[w >> 1][wn + j*16 + fr] = part[j];
    }
    __syncthreads();
    if (t < 128)
        ssbuf[((size_t)blockIdx.x*3 + m)*NTOK + n0 + t] = ssl[0][t] + ssl[1][t];
}

// ---------- gatefin3: k-split GEMV, wave-uniform W s_loads ----------
struct GfArgs { const float* tp[3]; };
__global__ __launch_bounds__(256)
void gatefin3_k(const float* __restrict__ x, const int* __restrict__ label,
                const float* __restrict__ Wn3, const float* __restrict__ bd3,
                const float* __restrict__ ssbuf, GfArgs gf,
                int* __restrict__ idx3, float* __restrict__ gw3)
{
    __shared__ float pd[3][64][26];
    const int t = threadIdx.x;
    const int tok = t & 63;
    const int qu = __builtin_amdgcn_readfirstlane(t >> 6);
    const int n = blockIdx.x * 64 + tok;

    float dots[3][8];
    #pragma unroll
    for (int m = 0; m < 3; m++)
        #pragma unroll
        for (int e = 0; e < 8; e++) dots[m][e] = 0.f;

    const float4* xp = (const float4*)(x + (size_t)n * DDIM + qu * 128);
    for (int c = 0; c < 8; c++){
        float4 xv[4];
        #pragma unroll
        for (int u = 0; u < 4; u++) xv[u] = xp[c*4 + u];
        #pragma unroll
        for (int kk = 0; kk < 16; kk++){
            float a = (kk & 2) ? ((kk & 1) ? xv[kk>>2].w : xv[kk>>2].z)
                               : ((kk & 1) ? xv[kk>>2].y : xv[kk>>2].x);
            int k = qu*128 + c*16 + kk;
            #pragma unroll
            for (int m = 0; m < 3; m++){
                const float* wr = Wn3 + ((size_t)m*DDIM + k)*8;
                float4 w0 = *(const float4*)wr;
                float4 w1 = *(const float4*)(wr + 4);
                dots[m][0] = fmaf(a, w0.x, dots[m][0]);
                dots[m][1] = fmaf(a, w0.y, dots[m][1]);
                dots[m][2] = fmaf(a, w0.z, dots[m][2]);
                dots[m][3] = fmaf(a, w0.w, dots[m][3]);
                dots[m][4] = fmaf(a, w1.x, dots[m][4]);
                dots[m][5] = fmaf(a, w1.y, dots[m][5]);
                dots[m][6] = fmaf(a, w1.z, dots[m][6]);
                dots[m][7] = fmaf(a, w1.w, dots[m][7]);
            }
        }
    }
    if (qu != 0){
        #pragma unroll
        for (int m = 0; m < 3; m++)
            #pragma unroll
            for (int e = 0; e < 8; e++) pd[qu-1][tok][m*8+e] = dots[m][e];
    }
    __syncthreads();
    if (qu == 0){
        #pragma unroll
        for (int qq = 0; qq < 3; qq++)
            #pragma unroll
            for (int m = 0; m < 3; m++)
                #pragma unroll
                for (int e = 0; e < 8; e++) dots[m][e] += pd[qq][tok][m*8+e];

        int lab = label[n];
        #pragma unroll
        for (int m = 0; m < 3; m++){
            float ss = ssbuf[(0*3+m)*(size_t)NTOK + n] + ssbuf[(1*3+m)*(size_t)NTOK + n];
            float scale = expf(fminf(gf.tp[m][0], LOG100));
            float inv = scale / (sqrtf(ss) + 1e-12f);
            float l8[8], mx = -1e30f;
            #pragma unroll
            for (int e = 0; e < 8; e++){
                l8[e] = (dots[m][e] + bd3[m*8+e]) * inv;
                mx = fmaxf(mx, l8[e]);
            }
            float g[8], s = 0.f;
            #pragma unroll
            for (int e = 0; e < 8; e++){ g[e] = expf(l8[e] - mx); s += g[e]; }
            #pragma unroll
            for (int e = 0; e < 8; e++) g[e] /= s;
            int e0 = 0; float b0 = g[0];
            #pragma unroll
            for (int e = 1; e < 8; e++) if (g[e] > b0){ b0 = g[e]; e0 = e; }
            int e1 = (e0 == 0) ? 1 : 0; float b1v = g[e1];
            #pragma unroll
            for (int e = 0; e < 8; e++) if (e != e0 && g[e] > b1v){ b1v = g[e]; e1 = e; }
            float maskv = (m == 0) ? 1.f : ((lab == m - 1) ? 1.f : 0.f);
            float s2 = b0 + b1v + 1e-9f;
            size_t base = (size_t)m * NSLOT + 2*(size_t)n;
            gw3[base]   = b0 / s2 * maskv;
            gw3[base+1] = b1v / s2 * maskv;
            idx3[base]   = e0;
            idx3[base+1] = e1;
        }
    }
}

// ---------- transposed-output bf16 MFMA GEMM core, 128x128, BK=32 ----------
template<int BGATHER, int OMODE>
__device__ __forceinline__
void gemm_core_t(short* As, short* Bs,
                 const unsigned short* __restrict__ AT, const unsigned short* __restrict__ Bv,
                 const float* __restrict__ bias, void* __restrict__ Cout,
                 int Kd, int Mld, int row0, int col0, int limitN,
                 const int* __restrict__ rowidx, const int* __restrict__ otok,
                 const float* __restrict__ gs)
{
    const int t = threadIdx.x;
    const int w = t >> 6, l = t & 63;
    const int qrow = l >> 2;
    const int kc = (l & 3) * 8;

    long arowg[2], browg[2];
    #pragma unroll
    for (int q = 0; q < 2; q++){
        arowg[q] = (long)(row0 + w*32 + q*16 + qrow) * Kd;
        int s = col0 + w*32 + q*16 + qrow;
        int gi = s;
        if (BGATHER) gi = (s < limitN) ? rowidx[s] : 0;
        browg[q] = (long)gi * Kd;
    }

    const int wm = (w >> 1) * 64, wn = (w & 1) * 64;
    const int fr = l & 15, fk = l >> 4;
    const int koff = fk * 8, fk4 = fk * 4;

    f32x4 acc[4][4];
    #pragma unroll
    for (int i = 0; i < 4; i++)
        #pragma unroll
        for (int j = 0; j < 4; j++) acc[i][j] = (f32x4){0.f, 0.f, 0.f, 0.f};

    for (int k0 = 0; k0 < Kd; k0 += 32){
        __syncthreads();
        #pragma unroll
        for (int q = 0; q < 2; q++) gload16(AT + arowg[q] + k0 + kc, As + w*1024 + q*512);
        #pragma unroll
        for (int q = 0; q < 2; q++) gload16(Bv + browg[q] + k0 + kc, Bs + w*1024 + q*512);
        __syncthreads();
        bf16x8 af[4], bfv[4];
        #pragma unroll
        for (int i = 0; i < 4; i++) af[i]  = *(const bf16x8*)&As[(wm + i*16 + fr)*32 + koff];
        #pragma unroll
        for (int j = 0; j < 4; j++) bfv[j] = *(const bf16x8*)&Bs[(wn + j*16 + fr)*32 + koff];
        __builtin_amdgcn_s_setprio(1);
        #pragma unroll
        for (int i = 0; i < 4; i++)
            #pragma unroll
            for (int j = 0; j < 4; j++)
                acc[i][j] = __builtin_amdgcn_mfma_f32_16x16x32_bf16(af[i], bfv[j], acc[i][j], 0, 0, 0);
        __builtin_amdgcn_s_setprio(0);
    }

    #pragma unroll
    for (int i = 0; i < 4; i++){
        const int mc = row0 + wm + i*16 + fk4;
        float4 bb = *(const float4*)(bias + mc);
        #pragma unroll
        for (int j = 0; j < 4; j++){
            int s = col0 + wn + j*16 + fr;
            if (s < limitN){
                if (OMODE == 1){
                    ushort4 u;
                    u.x = f2bf(fmaxf(acc[i][j][0] + bb.x, 0.f));
                    u.y = f2bf(fmaxf(acc[i][j][1] + bb.y, 0.f));
                    u.z = f2bf(fmaxf(acc[i][j][2] + bb.z, 0.f));
                    u.w = f2bf(fmaxf(acc[i][j][3] + bb.w, 0.f));
                    *(ushort4*)((unsigned short*)Cout + (long)s * Mld + mc) = u;
                } else {
                    int tk = otok[s];
                    float g = gs[s];
                    float* op = (float*)Cout + (long)tk * Mld + mc;
                    float4 c = *(const float4*)op;
                    c.x += g * (acc[i][j][0] + bb.x);
                    c.y += g * (acc[i][j][1] + bb.y);
                    c.z += g * (acc[i][j][2] + bb.z);
                    c.w += g * (acc[i][j][3] + bb.w);
                    *(float4*)op = c;
                }
            }
        }
    }
}

// ---------- same core at BK=64 (two 32-k sub-buffers; fewer barrier pairs) ----------
template<int BGATHER, int OMODE>
__device__ __forceinline__
void gemm_core_t64(short* As, short* Bs,
                   const unsigned short* __restrict__ AT, const unsigned short* __restrict__ Bv,
                   const float* __restrict__ bias, void* __restrict__ Cout,
                   int Kd, int Mld, int row0, int col0, int limitN,
                   const int* __restrict__ rowidx, const int* __restrict__ otok,
                   const float* __restrict__ gs)
{
    const int t = threadIdx.x;
    const int w = t >> 6, l = t & 63;
    const int qrow = l >> 2;
    const int seg = (l & 3) * 8;

    long arowg[2], browg[2];
    #pragma unroll
    for (int q = 0; q < 2; q++){
        arowg[q] = (long)(row0 + w*32 + q*16 + qrow) * Kd;
        int s = col0 + w*32 + q*16 + qrow;
        int gi = s;
        if (BGATHER) gi = (s < limitN) ? rowidx[s] : 0;
        browg[q] = (long)gi * Kd;
    }

    const int wm = (w >> 1) * 64, wn = (w & 1) * 64;
    const int fr = l & 15, fk = l >> 4;
    const int koff = fk * 8, fk4 = fk * 4;

    f32x4 acc[4][4];
    #pragma unroll
    for (int i = 0; i < 4; i++)
        #pragma unroll
        for (int j = 0; j < 4; j++) acc[i][j] = (f32x4){0.f, 0.f, 0.f, 0.f};

    for (int k0 = 0; k0 < Kd; k0 += 64){
        __syncthreads();
        #pragma unroll
        for (int ks = 0; ks < 2; ks++)
            #pragma unroll
            for (int q = 0; q < 2; q++)
                gload16(AT + arowg[q] + k0 + ks*32 + seg, As + ks*4096 + w*1024 + q*512);
        #pragma unroll
        for (int ks = 0; ks < 2; ks++)
            #pragma unroll
            for (int q = 0; q < 2; q++)
                gload16(Bv + browg[q] + k0 + ks*32 + seg, Bs + ks*4096 + w*1024 + q*512);
        __syncthreads();
        #pragma unroll
        for (int ks = 0; ks < 2; ks++){
            bf16x8 af[4], bfv[4];
            #pragma unroll
            for (int i = 0; i < 4; i++) af[i]  = *(const bf16x8*)&As[ks*4096 + (wm + i*16 + fr)*32 + koff];
            #pragma unroll
            for (int j = 0; j < 4; j++) bfv[j] = *(const bf16x8*)&Bs[ks*4096 + (wn + j*16 + fr)*32 + koff];
            __builtin_amdgcn_s_setprio(1);
            #pragma unroll
            for (int i = 0; i < 4; i++)
                #pragma unroll
                for (int j = 0; j < 4; j++)
                    acc[i][j] = __builtin_amdgcn_mfma_f32_16x16x32_bf16(af[i], bfv[j], acc[i][j], 0, 0, 0);
            __builtin_amdgcn_s_setprio(0);
        }
    }

    #pragma unroll
    for (int i = 0; i < 4; i++){
        const int mc = row0 + wm + i*16 + fk4;
        float4 bb = *(const float4*)(bias + mc);
        #pragma unroll
        for (int j = 0; j < 4; j++){
            int s = col0 + wn + j*16 + fr;
            if (s < limitN){
                if (OMODE == 1){
                    ushort4 u;
                    u.x = f2bf(fmaxf(acc[i][j][0] + bb.x, 0.f));
                    u.y = f2bf(fmaxf(acc[i][j][1] + bb.y, 0.f));
                    u.z = f2bf(fmaxf(acc[i][j][2] + bb.z, 0.f));
                    u.w = f2bf(fmaxf(acc[i][j][3] + bb.w, 0.f));
                    *(ushort4*)((unsigned short*)Cout + (long)s * Mld + mc) = u;
                } else {
                    int tk = otok[s];
                    float g = gs[s];
                    float* op = (float*)Cout + (long)tk * Mld + mc;
                    float4 c = *(const float4*)op;
                    c.x += g * (acc[i][j][0] + bb.x);
                    c.y += g * (acc[i][j][1] + bb.y);
                    c.z += g * (acc[i][j][2] + bb.z);
                    c.w += g * (acc[i][j][3] + bb.w);
                    *(float4*)op = c;
                }
            }
        }
    }
}

// ---------- y-GEMM core: 64 feat x 128 slots, BK=64 ----------
__device__ __forceinline__
void gemm_core_y64(short* lds,
                   const unsigned short* __restrict__ AT, const unsigned short* __restrict__ Bv,
                   const float* __restrict__ bias, float* __restrict__ out,
                   int row0, int col0, int limitN,
                   const int* __restrict__ otok, const float* __restrict__ gs)
{
    short* As = lds;
    short* Bs = lds + 4096;
    const int t = threadIdx.x, w = t >> 6, l = t & 63;
    const int seg = (l & 3) * 8;

    const long arow = (long)(row0 + w*16 + (l >> 2)) * HDIM;
    long brow[2];
    #pragma unroll
    for (int hh = 0; hh < 2; hh++)
        brow[hh] = (long)(col0 + w*32 + hh*16 + (l >> 2)) * HDIM;

    const int wm = (w >> 1) * 32, wn = (w & 1) * 64;
    const int fr = l & 15, fk = l >> 4;
    const int koff = fk * 8, fk4 = fk * 4;

    f32x4 acc[2][4];
    #pragma unroll
    for (int i = 0; i < 2; i++)
        #pragma unroll
        for (int j = 0; j < 4; j++) acc[i][j] = (f32x4){0.f, 0.f, 0.f, 0.f};

    for (int k0 = 0; k0 < HDIM; k0 += 64){
        __syncthreads();
        #pragma unroll
        for (int ks = 0; ks < 2; ks++)
            gload16(AT + arow + k0 + ks*32 + seg, As + ks*2048 + w*512);
        #pragma unroll
        for (int ks = 0; ks < 2; ks++)
            #pragma unroll
            for (int hh = 0; hh < 2; hh++)
                gload16(Bv + brow[hh] + k0 + ks*32 + seg, Bs + ks*4096 + w*1024 + hh*512);
        __syncthreads();
        #pragma unroll
        for (int ks = 0; ks < 2; ks++){
            bf16x8 af[2], bfv[4];
            #pragma unroll
            for (int i = 0; i < 2; i++)
                af[i] = *(const bf16x8*)&As[ks*2048 + (wm + i*16 + fr)*32 + koff];
            #pragma unroll
            for (int j = 0; j < 4; j++)
                bfv[j] = *(const bf16x8*)&Bs[ks*4096 + (wn + j*16 + fr)*32 + koff];
            __builtin_amdgcn_s_setprio(1);
            #pragma unroll
            for (int i = 0; i < 2; i++)
                #pragma unroll
                for (int j = 0; j < 4; j++)
                    acc[i][j] = __builtin_amdgcn_mfma_f32_16x16x32_bf16(af[i], bfv[j], acc[i][j], 0, 0, 0);
            __builtin_amdgcn_s_setprio(0);
        }
    }

    #pragma unroll
    for (int i = 0; i < 2; i++){
        const int mc = row0 + wm + i*16 + fk4;
        float4 bb = *(const float4*)(bias + mc);
        #pragma unroll
        for (int j = 0; j < 4; j++){
            int s = col0 + wn + j*16 + fr;
            if (s < limitN){
                int tk = otok[s];
                float g = gs[s];
                float* op = out + (long)tk * DDIM + mc;
                float4 c = *(const float4*)op;
                c.x += g * (acc[i][j][0] + bb.x);
                c.y += g * (acc[i][j][1] + bb.y);
                c.z += g * (acc[i][j][2] + bb.z);
                c.w += g * (acc[i][j][3] + bb.w);
                *(float4*)op = c;
            }
        }
    }
}

// ---------- serial GEMM (lowest tier) ----------
template<int BGATHER, int OMODE>
__global__ __launch_bounds__(256)
void mgemm3_k(const unsigned short* __restrict__ AT, const unsigned short* __restrict__ Bv,
              const float* __restrict__ bias, void* __restrict__ Cout,
              int Kd, int Mld,
              const int* __restrict__ rowidx, const int* __restrict__ otok,
              const float* __restrict__ gs, const int* __restrict__ cntp, int cnti)
{
    __shared__ __align__(16) short As[128*32];
    __shared__ __align__(16) short Bs[128*32];
    int limit = cntp[cnti]; if (limit > CAP) limit = CAP;
    int row0 = blockIdx.x * 128, col0 = blockIdx.y * 128;
    if (col0 >= limit) return;
    gemm_core_t<BGATHER, OMODE>(As, Bs, AT, Bv, bias, Cout, Kd, Mld,
                                row0, col0, limit, rowidx, otok, gs);
}

// ---------- generic grouped FFN dispatch (tier 0) ----------
// Job j[i] = {kind(0=h,1=y; >1 pad), model, expert, hbuf idx}
struct JobsArg { int4 j[4]; };
struct FfnP { const float* b1[3]; const float* b2[3]; };
__global__ __launch_bounds__(256)
void ffnG_k(const unsigned short* __restrict__ xb,
            const unsigned short* __restrict__ W1T3, const unsigned short* __restrict__ W2T3,
            FfnP fp,
            unsigned short* __restrict__ hb0, unsigned short* __restrict__ hb1,
            unsigned short* __restrict__ hb2, unsigned short* __restrict__ hb3,
            float* __restrict__ out,
            const int* __restrict__ tok3, const float* __restrict__ gslot3,
            const int* __restrict__ cntk3, JobsArg ja)
{
    __shared__ __align__(16) short lds[16384];   // 32KB
    const int bx = blockIdx.x;
    const int ji = blockIdx.y >> 3, sub = blockIdx.y & 7;
    const int4 J = ja.j[ji];
    if (J.x > 1) return;                 // padding slot
    const int m = J.y, e = J.z;
    unsigned short* hbuf = (J.w == 0) ? hb0 : (J.w == 1) ? hb1 : (J.w == 2) ? hb2 : hb3;
    const int g = m*NEXP + e;
    int limit = cntk3[m*16 + e]; if (limit > CAP) limit = CAP;
    const int col0 = bx * 128;
    if (col0 >= limit) return;
    if (J.x == 0){
        gemm_core_t64<1, 1>(lds, lds + 8192,
                            W1T3 + (size_t)g*HDIM*DDIM, xb, fp.b1[m] + (size_t)e*HDIM,
                            hbuf, DDIM, HDIM, sub*128, col0, limit,
                            tok3 + (size_t)g*CAP, nullptr, nullptr);
    } else {
        gemm_core_y64(lds, W2T3 + (size_t)g*DDIM*HDIM, hbuf, fp.b2[m] + (size_t)e*DDIM,
                      out, sub*64, col0, limit,
                      tok3 + (size_t)g*CAP, gslot3 + (size_t)g*CAP);
    }
}

// ---------- cross-model pipelined FFN (tier 1 fallback) ----------
__global__ __launch_bounds__(256)
void ffnA_k(const unsigned short* __restrict__ xb,
            const unsigned short* __restrict__ W1T3, const unsigned short* __restrict__ W2T3,
            FfnP fp, unsigned short* __restrict__ h0, unsigned short* __restrict__ h1,
            float* __restrict__ out,
            const int* __restrict__ tok3, const float* __restrict__ gslot3,
            const int* __restrict__ cntk3, int ge)
{
    __shared__ __align__(16) short lds[16384];   // 32KB
    const int bx = blockIdx.x, by = blockIdx.y;
    const int col0 = bx * 128;
    if (by < 8){
        if (ge >= 24) return;
        int m = ge >> 3, e = ge & 7;
        int limit = cntk3[m*16 + e]; if (limit > CAP) limit = CAP;
        if (col0 >= limit) return;
        unsigned short* hd = (ge & 1) ? h1 : h0;
        gemm_core_t64<1, 1>(lds, lds + 8192,
                            W1T3 + ((size_t)(m*8+e))*HDIM*DDIM, xb, fp.b1[m] + (size_t)e*HDIM,
                            hd, DDIM, HDIM, by*128, col0, limit,
                            tok3 + ((size_t)m*NEXP + e)*CAP, nullptr, nullptr);
    } else {
        int gy = ge - 1; if (gy < 0) return;
        int m = gy >> 3, e = gy & 7;
        int limit = cntk3[m*16 + e]; if (limit > CAP) limit = CAP;
        if (col0 >= limit) return;
        const unsigned short* hs = (gy & 1) ? h1 : h0;
        gemm_core_y64(lds, W2T3 + ((size_t)(m*8+e))*DDIM*HDIM, hs, fp.b2[m] + (size_t)e*DDIM,
                      out, (by-8)*64, col0, limit,
                      tok3 + ((size_t)m*NEXP + e)*CAP, gslot3 + ((size_t)m*NEXP + e)*CAP);
    }
}

// ---------- per-model pipelined FFN (lower tier) ----------
__global__ __launch_bounds__(256)
void ffnB_k(const unsigned short* __restrict__ xb,
            const unsigned short* __restrict__ W1T, const float* __restrict__ b1,
            const unsigned short* __restrict__ W2T, const float* __restrict__ b2,
            unsigned short* __restrict__ h0, unsigned short* __restrict__ h1,
            float* __restrict__ out,
            const int* __restrict__ tok, const float* __restrict__ gslot,
            const int* __restrict__ cntk, int eh)
{
    __shared__ __align__(16) short lds[16384];
    const int bx = blockIdx.x, by = blockIdx.y;
    const int col0 = bx * 128;
    if (by < 8){
        if (eh > 7) return;
        int limit = cntk[eh]; if (limit > CAP) limit = CAP;
        if (col0 >= limit) return;
        unsigned short* hd = (eh & 1) ? h1 : h0;
        gemm_core_t64<1, 1>(lds, lds + 8192,
                            W1T + (size_t)eh*HDIM*DDIM, xb, b1 + (size_t)eh*HDIM,
                            hd, DDIM, HDIM, by*128, col0, limit,
                            tok + (size_t)eh*CAP, nullptr, nullptr);
    } else {
        int ey = eh - 1; if (ey < 0) return;
        int limit = cntk[ey]; if (limit > CAP) limit = CAP;
        if (col0 >= limit) return;
        const unsigned short* hs = (ey & 1) ? h1 : h0;
        gemm_core_y64(lds, W2T + (size_t)ey*DDIM*HDIM, hs, b2 + (size_t)ey*DDIM,
                      out, (by-8)*64, col0, limit,
                      tok + (size_t)ey*CAP, gslot + (size_t)ey*CAP);
    }
}

// ---------- ranking (batched over 3 models) ----------
__global__ __launch_bounds__(1024)
void rank_count3_k(const int* __restrict__ idx3, const int* __restrict__ label,
                   int* __restrict__ bcnt3)
{
    __shared__ int c[NEXP];
    const int m = blockIdx.y;
    const int* idx = idx3 + (size_t)m * NSLOT;
    int t = threadIdx.x;
    if (t < NEXP) c[t] = 0;
    __syncthreads();
    int s = blockIdx.x * 1024 + t;
    int n = s >> 1;
    int e = idx[s];
    bool valid = (m == 0) || (label[n] == m - 1);
    if (valid) atomicAdd(&c[e], 1);
    __syncthreads();
    if (t < NEXP) bcnt3[((size_t)m*128 + blockIdx.x)*NEXP + t] = c[t];
}

__global__ void rank_scan3_k(const int* __restrict__ bcnt3, int* __restrict__ boff3,
                             int* __restrict__ cntk3)
{
    int m = blockIdx.x, e = threadIdx.x;
    if (e < NEXP){
        int run = 0;
        for (int b = 0; b < NSLOT/1024; b++){
            boff3[((size_t)m*128 + b)*NEXP + e] = run;
            run += bcnt3[((size_t)m*128 + b)*NEXP + e];
        }
        cntk3[m*16 + e] = run < CAP ? run : CAP;
    }
}

__global__ __launch_bounds__(1024)
void rank_assign3_k(const int* __restrict__ idx3, const int* __restrict__ label,
                    const int* __restrict__ boff3, const float* __restrict__ gw3,
                    const float* __restrict__ dscale,
                    int* __restrict__ tok3, float* __restrict__ gs3)
{
    __shared__ int wcnt[16][NEXP];
    __shared__ int woff[16][NEXP];
    const int m = blockIdx.y;
    const int* idx = idx3 + (size_t)m * NSLOT;
    const float* gw = gw3 + (size_t)m * NSLOT;
    int t = threadIdx.x;
    int s = blockIdx.x * 1024 + t;
    int n = s >> 1;
    int e = idx[s];
    bool valid = (m == 0) || (label[n] == m - 1);
    int w = t >> 6, lane = t & 63;
    unsigned long long lt = (lane == 0) ? 0ull : ((1ull << lane) - 1ull);
    int myrank = 0;
    #pragma unroll
    for (int ei = 0; ei < NEXP; ei++){
        unsigned long long bal = __ballot(valid && (e == ei));
        if (ei == e) myrank = __popcll(bal & lt);
        if (lane == 0) wcnt[w][ei] = __popcll(bal);
    }
    __syncthreads();
    if (t < NEXP){
        int run = boff3[((size_t)m*128 + blockIdx.x)*NEXP + t];
        for (int w2 = 0; w2 < 16; w2++){
            woff[w2][t] = run;
            run += wcnt[w2][t];
        }
    }
    __syncthreads();
    int pos = woff[w][e] + myrank;
    bool keep = valid && (pos < CAP);
    if (keep){
        float scale = (m > 0) ? dscale[0] : 1.f;
        tok3[((size_t)m*NEXP + e)*CAP + pos] = n;
        gs3[((size_t)m*NEXP + e)*CAP + pos] = gw[s] * scale;
    }
}

extern "C" void kernel_launch(void* const* d_in, const int* in_sizes, int n_in,
                              void* d_out, int out_size, void* d_ws, size_t ws_size,
                              hipStream_t stream)
{
    (void)in_sizes; (void)n_in; (void)out_size;
    const float* x      = (const float*)d_in[0];
    const int*   label  = (const int*)  d_in[1];
    const float* dscale = (const float*)d_in[2];
    float* out = (float*)d_out;

    const size_t XB  = (size_t)NTOK * DDIM * 2;            // 64MB
    const size_t HS  = (size_t)CAP * HDIM * 2;             // 32MB
    const size_t WPT = (size_t)3 * PROJ * DDIM * 2;        // 768KB
    const size_t SS  = (size_t)2 * 3 * NTOK * 4;           // 1.5MB
    const size_t WN  = (size_t)3 * DDIM * 8 * 4;           // 48KB
    const size_t SMALL = WPT + SS + WN + 256 +
                         (size_t)3*PROJ*NEXP*4 +
                         (size_t)3*NSLOT*4*2 +
                         (size_t)3*NEXP*CAP*4*2 +
                         (size_t)3*128*NEXP*4*2 + 256;
    const size_t W12A = (size_t)2 * 3 * NEXP * DDIM * HDIM * 2;  // 48MB
    const size_t W12B = (size_t)2 * NEXP * DDIM * HDIM * 2;      // 16MB
    const size_t common = XB + HS + SMALL;                       // includes h0

    int tier;
    if      (ws_size >= common + 3*HS + W12A) tier = 0;   // grouped schedule (4 h-buffers)
    else if (ws_size >= common + HS + W12A)   tier = 1;   // cross-model pipeline
    else if (ws_size >= common + HS + W12B)   tier = 2;   // per-model pipelined
    else if (ws_size >= common + W12B)        tier = 3;   // per-model serial
    else return;  // clean failure, not a fault

    char* p = (char*)d_ws;
    unsigned short* xb   = (unsigned short*)p; p += XB;
    unsigned short* h0   = (unsigned short*)p; p += HS;
    unsigned short* WpT3 = (unsigned short*)p; p += WPT;
    float* ssbuf = (float*)p;  p += SS;
    float* Wn3   = (float*)p;  p += WN;
    float* bd3   = (float*)p;  p += 256;
    float* simn3 = (float*)p;  p += (size_t)3*PROJ*NEXP*4;
    int*   idx3  = (int*)p;    p += (size_t)3*NSLOT*4;
    float* gw3   = (float*)p;  p += (size_t)3*NSLOT*4;
    int*   tok3  = (int*)p;    p += (size_t)3*NEXP*CAP*4;
    float* gslot3= (float*)p;  p += (size_t)3*NEXP*CAP*4;
    int*   bcnt3 = (int*)p;    p += (size_t)3*128*NEXP*4;
    int*   boff3 = (int*)p;    p += (size_t)3*128*NEXP*4;
    int*   cntk3 = (int*)p;    p += 256;
    unsigned short* h1 = nullptr;
    unsigned short* h2 = nullptr;
    unsigned short* h3 = nullptr;
    if (tier <= 2){ h1 = (unsigned short*)p; p += HS; }
    if (tier == 0){ h2 = (unsigned short*)p; p += HS; h3 = (unsigned short*)p; p += HS; }
    unsigned short* Wbuf = (unsigned short*)p;

    SimArgs sa; TpArgs ta; WprodArgs wa; PssArgs pa; GfArgs gf; W12P wp; FfnP fp;
    for (int m = 0; m < 3; m++){
        ta.Wp[m] = (const float*)d_in[3 + 8*m + 0];
        wa.Wp[m] = ta.Wp[m];
        wa.bp[m] = (const float*)d_in[3 + 8*m + 1];
        pa.bp[m] = wa.bp[m];
        sa.sim[m] = (const float*)d_in[3 + 8*m + 2];
        gf.tp[m] = (const float*)d_in[3 + 8*m + 3];
        wp.W1[m] = (const float*)d_in[3 + 8*m + 4];
        fp.b1[m] = (const float*)d_in[3 + 8*m + 5];
        wp.W2[m] = (const float*)d_in[3 + 8*m + 6];
        fp.b2[m] = (const float*)d_in[3 + 8*m + 7];
    }

    // ---- prep + gate ----
    init_k<<<dim3(NTOK*DDIM/4/256), dim3(256), 0, stream>>>(
        (const float4*)x, (ushort4*)xb, (float4*)out);
    simn3_k<<<dim3(3), dim3(256), 0, stream>>>(sa, simn3);
    transWp_k<<<dim3(PROJ/32, DDIM/32, 3), dim3(32,8), 0, stream>>>(ta, WpT3);
    wprod_k<<<dim3(3), dim3(256), 0, stream>>>(wa, simn3, Wn3, bd3);
    pss_k<<<dim3(2, NTOK/128, 3), dim3(256), 0, stream>>>(WpT3, xb, pa, ssbuf);
    gatefin3_k<<<dim3(NTOK/64), dim3(256), 0, stream>>>(
        x, label, Wn3, bd3, ssbuf, gf, idx3, gw3);

    // ---- ranking ----
    rank_count3_k<<<dim3(NSLOT/1024, 3), dim3(1024), 0, stream>>>(idx3, label, bcnt3);
    rank_scan3_k<<<dim3(3), dim3(64), 0, stream>>>(bcnt3, boff3, cntk3);
    rank_assign3_k<<<dim3(NSLOT/1024, 3), dim3(1024), 0, stream>>>(
        idx3, label, boff3, gw3, dscale, tok3, gslot3);

    // ---- FFN ----
    if (tier <= 1){
        unsigned short* W1T3 = Wbuf;
        unsigned short* W2T3 = Wbuf + (size_t)3*NEXP*DDIM*HDIM;
        transW12all_k<<<dim3(32, 32, 48), dim3(32,8), 0, stream>>>(wp, W1T3, W2T3);
        if (tier == 0){
            // 13-step grouped schedule (2 experts per group, 4 h-buffers).
            // Job = {kind(0=h,1=y,9=pad), model, expert, hbuf}
            static const int S[13][4][4] = {
                {{0,0,0,0},{0,0,1,1},{9,0,0,0},{9,0,0,0}},
                {{0,0,2,2},{0,0,3,3},{1,0,0,0},{1,0,1,1}},
                {{0,0,4,0},{0,0,5,1},{1,0,2,2},{1,0,3,3}},
                {{0,0,6,2},{0,0,7,3},{1,0,4,0},{1,0,5,1}},
                {{0,1,0,0},{0,2,0,1},{1,0,6,2},{1,0,7,3}},
                {{0,1,1,2},{0,2,1,3},{1,1,0,0},{1,2,0,1}},
                {{0,1,2,0},{0,2,2,1},{1,1,1,2},{1,2,1,3}},
                {{0,1,3,2},{0,2,3,3},{1,1,2,0},{1,2,2,1}},
                {{0,1,4,0},{0,2,4,1},{1,1,3,2},{1,2,3,3}},
                {{0,1,5,2},{0,2,5,3},{1,1,4,0},{1,2,4,1}},
                {{0,1,6,0},{0,2,6,1},{1,1,5,2},{1,2,5,3}},
                {{0,1,7,2},{0,2,7,3},{1,1,6,0},{1,2,6,1}},
                {{1,1,7,2},{1,2,7,3},{9,0,0,0},{9,0,0,0}},
            };
            static const int NJ[13] = {2,4,4,4,4,4,4,4,4,4,4,4,2};
            for (int d = 0; d < 13; d++){
                JobsArg ja;
                for (int i = 0; i < 4; i++)
                    ja.j[i] = make_int4(S[d][i][0], S[d][i][1], S[d][i][2], S[d][i][3]);
                ffnG_k<<<dim3(128, 8*NJ[d]), 256, 0, stream>>>(
                    xb, W1T3, W2T3, fp, h0, h1, h2, h3, out, tok3, gslot3, cntk3, ja);
            }
        } else {
            for (int ge = 0; ge <= 24; ge++)
                ffnA_k<<<dim3(128, 16), 256, 0, stream>>>(
                    xb, W1T3, W2T3, fp, h0, h1, out, tok3, gslot3, cntk3, ge);
        }
    } else {
        unsigned short* W1T = Wbuf;
        unsigned short* W2T = Wbuf + (size_t)NEXP*DDIM*HDIM;
        for (int m = 0; m < 3; m++){
            trans2_k<<<dim3(32, 32, 16), dim3(32,8), 0, stream>>>(wp.W1[m], wp.W2[m], W1T, W2T);
            const int* tokm = tok3 + (size_t)m*NEXP*CAP;
            const float* gsm = gslot3 + (size_t)m*NEXP*CAP;
            const int* cntm = cntk3 + m*16;
            if (tier == 2){
                for (int eh = 0; eh <= 8; eh++)
                    ffnB_k<<<dim3(128, 16), 256, 0, stream>>>(
                        xb, W1T, fp.b1[m], W2T, fp.b2[m], h0, h1, out, tokm, gsm, cntm, eh);
            } else {
                for (int e = 0; e < NEXP; e++){
                    mgemm3_k<1, 1><<<dim3(HDIM/128, CAP/128), 256, 0, stream>>>(
                        W1T + (size_t)e*HDIM*DDIM, xb, fp.b1[m] + (size_t)e*HDIM, h0,
                        DDIM, HDIM, tokm + (size_t)e*CAP, nullptr, nullptr, cntm, e);
                    mgemm3_k<0, 3><<<dim3(DDIM/128, CAP/128), 256, 0, stream>>>(
                        W2T + (size_t)e*DDIM*HDIM, h0, fp.b2[m] + (size_t)e*DDIM, out,
                        HDIM, DDIM, nullptr, tokm + (size_t)e*CAP, gsm + (size_t)e*CAP, cntm, e);
                }
            }
        }
    }
}